// Round 11
// baseline (882.062 us; speedup 1.0000x reference)
//
#include <hip/hip_runtime.h>
#include <math.h>

#define BB 128
#define SS 80
#define HH 512
#define TT 27      // T-1
#define TFULL 28
#define VV 8000

typedef __attribute__((ext_vector_type(4))) float f32x4;
typedef __attribute__((ext_vector_type(8))) short bfrag;

// ---------------- fp32 workspace layout (floats) ----------------
#define OFF_VA   0
#define OFF_VB   512
#define OFF_U    1024
#define OFF_PART 1536
#define OFF_CTX  17920
#define OFF_GB   83456
#define OFF_XG   345600          // 3456*2048 (xg + gb folded)
#define OFF_BAR  7423488         // barrier region (~66K uints)
#define FP32_WS_FLOATS 7489536
// ---------------- bf16 workspace (ushort offsets from bf16 base) ----------------
#define O_H3     0               // 28*128 rows x 1024  [hi|lo] compact split
#define O_WHHC   3670016         // 2048 quad rows x 1024 [hi|lo] (r -> gate r&3, k r>>2)
#define O_R      5767168
#define O_A3X    O_R             // 3456 x 3072
#define O_B3X    (O_R + 10616832)// 2048 x 3072
#define O_B3L    O_R             // 8000 x 1536 (overlays A3X/B3X after xg gemm)

#define BAR_STRIDE 2048          // 8 KB between barrier lines -> distinct L3 slices

__device__ __forceinline__ unsigned short f2bf(float x) {
    unsigned int u = __float_as_uint(x);
    unsigned int r = (u + 0x7fff + ((u >> 16) & 1)) >> 16;
    return (unsigned short)r;
}
__device__ __forceinline__ float bf2f(unsigned short h) {
    return __uint_as_float(((unsigned int)h) << 16);
}
__device__ __forceinline__ void gload16(void* lds, const void* g) {
    __builtin_amdgcn_global_load_lds(
        (__attribute__((address_space(1))) void*)g,
        (__attribute__((address_space(3))) void*)lds, 16, 0, 0);
}

// ---- two-level tree barrier v2 (R11): 16 teams x 16 blocks, SLICE-SPREAD ----
// R10 evidence: 8 teams x 32 on 64B-apart lines gave 14.5us/step -> team lines
// likely shared one L3 slice (coarse interleave), serializing all arrivals.
// Now: team arrive-counters 8KB apart (own slice each), release words on
// separate 8KB pages, fan-in 16. Expect 16 parallel arrivals/line ~1-2us.
// layout (uint idx from base): [0]=global, [256+t*2048]=team_arrive t=0..15,
// [256+(16+t)*2048]=team_release
__device__ __forceinline__ void gbar2(unsigned* base, int team, unsigned phase) {
    __syncthreads();
    if (threadIdx.x == 0) {
        __threadfence();   // release: make this block's H3 stores visible
        unsigned* ta = base + 256 + team * BAR_STRIDE;
        unsigned* tr = base + 256 + (16 + team) * BAR_STRIDE;
        unsigned a = __hip_atomic_fetch_add(ta, 1u, __ATOMIC_RELAXED, __HIP_MEMORY_SCOPE_AGENT);
        if (a == 16u * phase - 1u) {
            // last arriver of this team for this phase
            __hip_atomic_fetch_add(base, 1u, __ATOMIC_RELAXED, __HIP_MEMORY_SCOPE_AGENT);
            while (__hip_atomic_load(base, __ATOMIC_RELAXED, __HIP_MEMORY_SCOPE_AGENT) < 16u * phase)
                __builtin_amdgcn_s_sleep(1);
            __hip_atomic_store(tr, phase, __ATOMIC_RELAXED, __HIP_MEMORY_SCOPE_AGENT);
        } else {
            while (__hip_atomic_load(tr, __ATOMIC_RELAXED, __HIP_MEMORY_SCOPE_AGENT) < phase)
                __builtin_amdgcn_s_sleep(4);
        }
        __builtin_amdgcn_fence(__ATOMIC_ACQUIRE, "agent");
    }
    __syncthreads();
}

__global__ __launch_bounds__(64) void zero_bar(unsigned* b) {
    int i = threadIdx.x;
    if (i == 0) b[0] = 0u;
    if (i < 32) b[256 + i * BAR_STRIDE] = 0u;
}

// ---------- split-bf16 conversion (3K-wide forms, for GEMM operands) ----------
// dst row r (3K wide): A-side: [hi | hi | lo]  B-side: [hi | lo | hi]
// mode 0: src row = r ; mode 1: gather emb row = gidx[(r&127)*28 + (r>>7)]
__global__ __launch_bounds__(256) void conv_split(
    const float* __restrict__ src, int ld, int koff, int K,
    int mode, int bside, const int* __restrict__ gidx,
    unsigned short* __restrict__ dst)
{
    int r = blockIdx.x;
    int sr = r;
    if (mode == 1) { int b = r & 127, t = r >> 7; sr = gidx[b * TFULL + t]; }
    const float* s = src + (size_t)sr * ld + koff;
    unsigned short* d = dst + (size_t)r * (3 * K);
    int off_mid = bside ? 2 * K : K;   // where the duplicated hi goes
    int off_lo  = bside ? K : 2 * K;
    for (int c = threadIdx.x * 4; c < K; c += 1024) {
        float4 v = *(const float4*)(s + c);
        ushort4 hi, lo;
        hi.x = f2bf(v.x); lo.x = f2bf(v.x - bf2f(hi.x));
        hi.y = f2bf(v.y); lo.y = f2bf(v.y - bf2f(hi.y));
        hi.z = f2bf(v.z); lo.z = f2bf(v.z - bf2f(hi.z));
        hi.w = f2bf(v.w); lo.w = f2bf(v.w - bf2f(hi.w));
        *(ushort4*)(d + c) = hi;
        *(ushort4*)(d + off_mid + c) = hi;
        *(ushort4*)(d + off_lo + c) = lo;
    }
}

// compact [hi|lo] split (1024-wide rows of 512 source floats).
// mode 0: src row = r ; mode 2: quad-interleave (src row = (r&3)*512 + (r>>2))
__global__ __launch_bounds__(256) void conv_splitc(
    const float* __restrict__ src, int mode, unsigned short* __restrict__ dst)
{
    int r = blockIdx.x;
    int sr = (mode == 2) ? (r & 3) * 512 + (r >> 2) : r;
    const float* s = src + (size_t)sr * 512;
    unsigned short* d = dst + (size_t)r * 1024;
    int c = threadIdx.x * 2;
    float2 v = *(const float2*)(s + c);
    unsigned short hx = f2bf(v.x), hy = f2bf(v.y);
    d[c] = hx; d[c + 1] = hy;
    d[512 + c] = f2bf(v.x - bf2f(hx));
    d[512 + c + 1] = f2bf(v.y - bf2f(hy));
}

// ---------- bf16 MFMA GEMM: C = A3 @ B3^T (+bias)(+addmat), 128x128 tile, BK=64 ----------
// A3 rows have stride astride; if ahalf, A is compact [hi|lo] (1024) and
// logical k0 maps as eff = k0<512 ? k0 : k0-512 (region1->hi, region2->lo).
// outMode 0: C[m*N+n]   outMode 1: C[((m&127)*27 + (m>>7))*8000 + n]
__global__ __launch_bounds__(256) void gemm_bf16_nt(
    int M, int N, int K3,
    const unsigned short* __restrict__ A3, int astride, int ahalf,
    const unsigned short* __restrict__ B3,
    const float* __restrict__ bias,
    const float* __restrict__ addmat,
    float* __restrict__ C, int outMode)
{
    __shared__ unsigned short Asm[128 * 64];
    __shared__ unsigned short Bsm[128 * 64];
    int tid = threadIdx.x, wave = tid >> 6, lane = tid & 63;

    // ---- block swizzle: XCD-contiguous lid, then GROUP=9 m-fast supertiles ----
    int nT = gridDim.x, mT = gridDim.y;
    int p = blockIdx.y * nT + blockIdx.x;
    int nwg = nT * mT;
    int q = nwg >> 3, rr = nwg & 7;
    int xcd = p & 7, pos = p >> 3;
    int lid = (xcd < rr) ? (xcd * (q + 1) + pos) : (rr * (q + 1) + (xcd - rr) * q + pos);
    const int GROUP = 9;
    int width = GROUP * nT;
    int gid2 = lid / width;
    int first_m = gid2 * GROUP;
    int gsz = mT - first_m; if (gsz > GROUP) gsz = GROUP;
    int rem = lid - gid2 * width;
    int mt = first_m + rem % gsz;
    int nt = rem / gsz;
    int m0 = mt * 128, n0 = nt * 128;

    int wm0 = (wave >> 1) * 64, wn0 = (wave & 1) * 64;
    f32x4 acc[4][4];
    #pragma unroll
    for (int i = 0; i < 4; ++i)
        #pragma unroll
        for (int j = 0; j < 4; ++j) acc[i][j] = (f32x4){0.f, 0.f, 0.f, 0.f};

    int srow8 = lane >> 3;             // row within 8-row chunk
    int schunk = lane & 7;             // 16B chunk within 128B row
    for (int k0 = 0; k0 < K3; k0 += 64) {
        int ek0 = ahalf ? (k0 >= 512 ? k0 - 512 : k0) : k0;
        #pragma unroll
        for (int rep = 0; rep < 4; ++rep) {
            int ci = wave * 4 + rep;
            int row = ci * 8 + srow8;
            int sc = schunk ^ (row & 7);
            int gm = m0 + row; if (gm >= M) gm = M - 1;
            gload16(Asm + ci * 512 + lane * 8,
                    A3 + (size_t)gm * astride + ek0 + sc * 8);
            int gn = n0 + row; if (gn >= N) gn = N - 1;
            gload16(Bsm + ci * 512 + lane * 8,
                    B3 + (size_t)gn * K3 + k0 + sc * 8);
        }
        __syncthreads();
        #pragma unroll
        for (int ks = 0; ks < 2; ++ks) {
            bfrag a[4], b[4];
            #pragma unroll
            for (int i = 0; i < 4; ++i) {
                int ar = wm0 + i * 16 + (lane & 15);
                int ab = (ar * 128 + ks * 64 + (lane >> 4) * 16) ^ ((ar & 7) << 4);
                a[i] = *(const bfrag*)((const char*)Asm + ab);
                int br = wn0 + i * 16 + (lane & 15);
                int bb = (br * 128 + ks * 64 + (lane >> 4) * 16) ^ ((br & 7) << 4);
                b[i] = *(const bfrag*)((const char*)Bsm + bb);
            }
            #pragma unroll
            for (int i = 0; i < 4; ++i)
                #pragma unroll
                for (int j = 0; j < 4; ++j)
                    acc[i][j] = __builtin_amdgcn_mfma_f32_16x16x32_bf16(a[i], b[j], acc[i][j], 0, 0, 0);
        }
        __syncthreads();
    }
    #pragma unroll
    for (int i = 0; i < 4; ++i) {
        #pragma unroll
        for (int r = 0; r < 4; ++r) {
            int m = m0 + wm0 + i * 16 + ((lane >> 4) << 2) + r;
            if (m >= M) continue;
            #pragma unroll
            for (int j = 0; j < 4; ++j) {
                int n = n0 + wn0 + j * 16 + (lane & 15);
                if (n >= N) continue;
                float v = acc[i][j][r];
                if (bias) v += bias[n];
                if (addmat) v += addmat[(size_t)(m & 127) * 2048 + n];
                size_t oi;
                if (outMode == 0) oi = (size_t)m * N + n;
                else { int bb2 = m & 127, tt = m >> 7; oi = ((size_t)bb2 * TT + tt) * (size_t)VV + n; }
                C[oi] = v;
            }
        }
    }
}

// ---------- persistent LSTM v3 (R9-proven compute) + slice-spread tree barrier ----------
// Block (bg,ns) = (wg>>6, wg&63): M = 32 b-rows [bg*32..), N = 32 quad rows
// [ns*32, ns*32+32) => k in [ns*8, ns*8+8) x 4 gates.
// W slice compact [hi|lo] (64KB) staged once; A compact (64KB) per step.
// Wave wv = (mi=wv>>1, nj=wv&1) owns one 16x16 quadrant, full K=1536 via
// region remaps. c-state in registers; shfl-down gate gather epilogue.
__global__ __launch_bounds__(256, 1) void lstm_persist3(
    unsigned short* __restrict__ H3,        // 28*128 x 1024 [hi|lo]
    const unsigned short* __restrict__ W3C, // 2048 quad rows x 1024 [hi|lo]
    const float* __restrict__ xgb,          // 3456 x 2048 (xg + gb)
    unsigned* bar)
{
    __shared__ unsigned short Wl[32 * 1024];   // 65536 B
    __shared__ unsigned short Al[32 * 1024];   // 65536 B

    int tid = threadIdx.x, wv = tid >> 6, lane = tid & 63;
    int wg = blockIdx.x;
    int bg = wg >> 6, ns = wg & 63;
    int team = wg >> 4;                        // 16 teams of 16 blocks
    int b0 = bg * 32;
    int mi = wv >> 1, nj = wv & 1;
    int l15 = lane & 15, g4 = (lane >> 4) << 4;
    unsigned phase = 0;
    float creg[4] = {0.f, 0.f, 0.f, 0.f};

    // stage W slice once: 32 rows x 1024 elems (128 x 16B chunks per row)
    {
        const unsigned short* Wsrc = W3C + (size_t)(ns * 32) * 1024;
        #pragma unroll
        for (int j = 0; j < 16; ++j) {
            int ci = j * 256 + tid;
            int row = ci >> 7, cc = ci & 127;
            int sc = cc ^ (row & 7);
            gload16(Wl + ci * 8, Wsrc + (size_t)row * 1024 + sc * 8);
        }
        asm volatile("s_waitcnt vmcnt(0)" ::: "memory");
    }
    __syncthreads();

    int arow = mi * 16 + l15;   // A LDS row (m)
    int brow = nj * 16 + l15;   // W LDS row (n quad)
    int g = brow & 3;           // gate of this lane's n
    int kglob = ns * 8 + (brow >> 2);

    for (int t = 0; t < TT; ++t) {
        const unsigned short* Asrc = H3 + ((size_t)t * 128 + b0) * 1024;
        #pragma unroll
        for (int j = 0; j < 16; ++j) {
            int ci = j * 256 + tid;
            int row = ci >> 7, cc = ci & 127;
            int sc = cc ^ (row & 7);
            gload16(Al + ci * 8, Asrc + (size_t)row * 1024 + sc * 8);
        }
        asm volatile("s_waitcnt vmcnt(0)" ::: "memory");
        __syncthreads();

        f32x4 accA = (f32x4){0.f, 0.f, 0.f, 0.f};
        f32x4 accB = accA;
        #pragma unroll
        for (int q = 0; q < 24; ++q) {
            int c0 = 2 * q, c1 = 2 * q + 1;
            int ac0 = (c0 < 16) ? c0 : c0 - 16;
            int ac1 = (c1 < 16) ? c1 : c1 - 16;
            int bc0 = (c0 < 32) ? c0 : c0 - 32;
            int bc1 = (c1 < 32) ? c1 : c1 - 32;
            int ab0 = (arow * 2048 + ac0 * 64 + g4) ^ ((l15 & 7) << 4);
            int bb0 = (brow * 2048 + bc0 * 64 + g4) ^ ((l15 & 7) << 4);
            int ab1 = (arow * 2048 + ac1 * 64 + g4) ^ ((l15 & 7) << 4);
            int bb1 = (brow * 2048 + bc1 * 64 + g4) ^ ((l15 & 7) << 4);
            bfrag a0 = *(const bfrag*)((const char*)Al + ab0);
            bfrag w0 = *(const bfrag*)((const char*)Wl + bb0);
            bfrag a1 = *(const bfrag*)((const char*)Al + ab1);
            bfrag w1 = *(const bfrag*)((const char*)Wl + bb1);
            accA = __builtin_amdgcn_mfma_f32_16x16x32_bf16(a0, w0, accA, 0, 0, 0);
            accB = __builtin_amdgcn_mfma_f32_16x16x32_bf16(a1, w1, accB, 0, 0, 0);
        }
        f32x4 accT = accA + accB;

        #pragma unroll
        for (int r = 0; r < 4; ++r) {
            int m_local = mi * 16 + ((lane >> 4) << 2) + r;
            int b = b0 + m_local;
            float v = accT[r] +
                      xgb[(((size_t)t * 128 + b) << 11) + (size_t)g * 512 + kglob];
            float f1 = __shfl_down(v, 1);
            float f2 = __shfl_down(v, 2);
            float f3 = __shfl_down(v, 3);
            if ((lane & 3) == 0) {
                float si = 1.f / (1.f + expf(-v));
                float sf = 1.f / (1.f + expf(-f1));
                float tg = tanhf(f2);
                float so = 1.f / (1.f + expf(-f3));
                float cn = sf * creg[r] + si * tg;
                float hn = so * tanhf(cn);
                creg[r] = cn;
                unsigned short hi = f2bf(hn);
                unsigned short lo = f2bf(hn - bf2f(hi));
                unsigned short* hr = H3 + ((size_t)(t + 1) * 128 + b) * 1024;
                hr[kglob] = hi; hr[512 + kglob] = lo;
            }
        }
        if (t != TT - 1) { ++phase; gbar2(bar, team, phase); }
    }
}

// ---------- small helpers ----------
__global__ __launch_bounds__(512) void matvec_col_partial(
    const float* __restrict__ W, int ldw, int koff,
    const float* __restrict__ vin, float* __restrict__ part)
{
    int k = threadIdx.x;
    int o0 = blockIdx.x * 16;
    float acc = 0.f;
    #pragma unroll
    for (int o = 0; o < 16; ++o)
        acc += W[(size_t)(o0 + o) * ldw + koff + k] * vin[o0 + o];
    part[blockIdx.x * 512 + k] = acc;
}

__global__ __launch_bounds__(512) void matvec_combine(
    const float* __restrict__ part, float* __restrict__ vout)
{
    int k = threadIdx.x;
    float s = 0.f;
    #pragma unroll
    for (int c = 0; c < 32; ++c) s += part[c * 512 + k];
    vout[k] = s;
}

__global__ __launch_bounds__(256) void attn_ctx(
    const float* __restrict__ enc, const float* __restrict__ u,
    float* __restrict__ ctx)
{
    __shared__ float su[HH];
    __shared__ float sw[SS];
    __shared__ float ssum;
    int b = blockIdx.x, tid = threadIdx.x;
    su[tid] = u[tid];
    su[tid + 256] = u[tid + 256];
    __syncthreads();
    const float* eb = enc + (size_t)b * SS * HH;
    int wave = tid >> 6, lane = tid & 63;
    for (int s = wave; s < SS; s += 4) {
        const float* row = eb + s * HH;
        float acc = 0.f;
        for (int k = lane; k < HH; k += 64) acc += row[k] * su[k];
        #pragma unroll
        for (int off = 32; off; off >>= 1) acc += __shfl_down(acc, off);
        if (lane == 0) sw[s] = acc;
    }
    __syncthreads();
    if (tid == 0) {
        float mx = sw[0];
        for (int s = 1; s < SS; ++s) mx = fmaxf(mx, sw[s]);
        float sum = 0.f;
        for (int s = 0; s < SS; ++s) { float e = expf(sw[s] - mx); sw[s] = e; sum += e; }
        ssum = sum;
    }
    __syncthreads();
    float inv = 1.0f / ssum;
    for (int k = tid; k < HH; k += 256) {
        float acc = 0.f;
        #pragma unroll 4
        for (int s = 0; s < SS; ++s) acc += sw[s] * eb[s * HH + k];
        ctx[(size_t)b * HH + k] = acc * inv;
    }
}

// fp32 vector GEMM, kept only for gbase (ctx @ Wc^T + b_ih + b_hh)
__global__ __launch_bounds__(256) void gemm_nt(
    int M, int N, int K,
    const float* __restrict__ A, int lda,
    const float* __restrict__ Bm, int ldb, int kob,
    const float* __restrict__ bias1, const float* __restrict__ bias2,
    float* __restrict__ C)
{
    __shared__ float As[16][132];
    __shared__ float Bs[16][132];
    int tid = threadIdx.x;
    int m0 = blockIdx.y * 128, n0 = blockIdx.x * 128;
    int tn = tid & 15, tm = tid >> 4;
    float acc[8][8];
    #pragma unroll
    for (int i = 0; i < 8; ++i)
        #pragma unroll
        for (int j = 0; j < 8; ++j) acc[i][j] = 0.f;
    int lr = tid >> 2;
    int lk = (tid & 3) * 4;
    for (int k0 = 0; k0 < K; k0 += 16) {
        #pragma unroll
        for (int half = 0; half < 2; ++half) {
            int mr = lr + half * 64;
            int m = m0 + mr;
            float4 va = make_float4(0.f, 0.f, 0.f, 0.f);
            if (m < M) va = *(const float4*)(A + (size_t)m * lda + k0 + lk);
            As[lk + 0][mr] = va.x; As[lk + 1][mr] = va.y;
            As[lk + 2][mr] = va.z; As[lk + 3][mr] = va.w;
            int n = n0 + mr;
            float4 vb = make_float4(0.f, 0.f, 0.f, 0.f);
            if (n < N) vb = *(const float4*)(Bm + (size_t)n * ldb + kob + k0 + lk);
            Bs[lk + 0][mr] = vb.x; Bs[lk + 1][mr] = vb.y;
            Bs[lk + 2][mr] = vb.z; Bs[lk + 3][mr] = vb.w;
        }
        __syncthreads();
        #pragma unroll
        for (int kk = 0; kk < 16; ++kk) {
            float4 a0 = *(const float4*)&As[kk][tm * 8];
            float4 a1 = *(const float4*)&As[kk][tm * 8 + 4];
            float4 b0 = *(const float4*)&Bs[kk][tn * 8];
            float4 b1 = *(const float4*)&Bs[kk][tn * 8 + 4];
            float av[8] = {a0.x, a0.y, a0.z, a0.w, a1.x, a1.y, a1.z, a1.w};
            float bv[8] = {b0.x, b0.y, b0.z, b0.w, b1.x, b1.y, b1.z, b1.w};
            #pragma unroll
            for (int i = 0; i < 8; ++i)
                #pragma unroll
                for (int j = 0; j < 8; ++j)
                    acc[i][j] += av[i] * bv[j];
        }
        __syncthreads();
    }
    #pragma unroll
    for (int i = 0; i < 8; ++i) {
        int m = m0 + tm * 8 + i;
        if (m >= M) continue;
        #pragma unroll
        for (int j = 0; j < 8; ++j) {
            int n = n0 + tn * 8 + j;
            if (n >= N) continue;
            float v = acc[i][j];
            if (bias1) v += bias1[n];
            if (bias2) v += bias2[n];
            C[(size_t)m * N + n] = v;
        }
    }
}

__global__ __launch_bounds__(256) void argmax_k(
    const float* __restrict__ logits, float* __restrict__ preds)
{
    int r = blockIdx.x * 4 + (threadIdx.x >> 6);
    int lane = threadIdx.x & 63;
    const float* row = logits + (size_t)r * VV;
    float best = -INFINITY;
    int bi = 0;
    for (int v = lane; v < VV; v += 64) {
        float x = row[v];
        if (x > best) { best = x; bi = v; }
    }
    #pragma unroll
    for (int off = 32; off; off >>= 1) {
        float ob = __shfl_down(best, off);
        int oi = __shfl_down(bi, off);
        if (ob > best || (ob == best && oi < bi)) { best = ob; bi = oi; }
    }
    if (lane == 0) preds[r] = (float)bi;
}

extern "C" void kernel_launch(void* const* d_in, const int* in_sizes, int n_in,
                              void* d_out, int out_size, void* d_ws, size_t ws_size,
                              hipStream_t stream) {
    const float* ehs   = (const float*)d_in[0];
    const float* enc   = (const float*)d_in[1];
    const int*   tgt   = (const int*)d_in[2];
    const float* emb   = (const float*)d_in[4];
    const float* fc1w  = (const float*)d_in[5];
    const float* fc2w  = (const float*)d_in[7];
    const float* fc3w  = (const float*)d_in[9];
    const float* fc4w  = (const float*)d_in[11];
    const float* attnw = (const float*)d_in[13];
    const float* wih   = (const float*)d_in[14];
    const float* whh   = (const float*)d_in[15];
    const float* bih   = (const float*)d_in[16];
    const float* bhh   = (const float*)d_in[17];
    const float* outw  = (const float*)d_in[18];
    const float* outb  = (const float*)d_in[19];
    float* out = (float*)d_out;
    float* ws  = (float*)d_ws;

    float* vA   = ws + OFF_VA;
    float* vB   = ws + OFF_VB;
    float* u    = ws + OFF_U;
    float* part = ws + OFF_PART;
    float* ctx  = ws + OFF_CTX;
    float* gb   = ws + OFF_GB;
    float* xg   = ws + OFF_XG;
    unsigned* bar = (unsigned*)(ws + OFF_BAR);
    unsigned short* bfb = (unsigned short*)(ws + FP32_WS_FLOATS);
    unsigned short* H3   = bfb + O_H3;
    unsigned short* WHHC = bfb + O_WHHC;
    unsigned short* A3X  = bfb + O_A3X;
    unsigned short* B3X  = bfb + O_B3X;
    unsigned short* B3L  = bfb + O_B3L;

    // u = W1e^T W2^T W3^T W4^T attn_w
    matvec_col_partial<<<32, 512, 0, stream>>>(fc4w, 512, 0, attnw, part);
    matvec_combine<<<1, 512, 0, stream>>>(part, vA);
    matvec_col_partial<<<32, 512, 0, stream>>>(fc3w, 512, 0, vA, part);
    matvec_combine<<<1, 512, 0, stream>>>(part, vB);
    matvec_col_partial<<<32, 512, 0, stream>>>(fc2w, 512, 0, vB, part);
    matvec_combine<<<1, 512, 0, stream>>>(part, vA);
    matvec_col_partial<<<32, 512, 0, stream>>>(fc1w, 1024, 0, vA, part);
    matvec_combine<<<1, 512, 0, stream>>>(part, u);

    attn_ctx<<<128, 256, 0, stream>>>(enc, u, ctx);

    // gbase = ctx @ Wc^T + b_ih + b_hh  (fp32 path, tiny)
    {
        dim3 g(16, 1);
        gemm_nt<<<g, 256, 0, stream>>>(128, 2048, 512, ctx, 512,
                                       wih, 1536, 1024, bih, bhh, gb);
    }

    // xgb = gather(emb, tgt) @ Wx^T + gb  via split-bf16 MFMA
    conv_split<<<2048, 256, 0, stream>>>(wih, 1536, 0, 1024, 0, 1, nullptr, B3X);
    conv_split<<<3456, 256, 0, stream>>>(emb, 1024, 0, 1024, 1, 0, tgt, A3X);
    {
        dim3 g(16, 27);
        gemm_bf16_nt<<<g, 256, 0, stream>>>(3456, 2048, 3072, A3X, 3072, 0, B3X,
                                            nullptr, gb, xg, 0);
    }

    // B3L overlays A3X/B3X — only after the xg gemm
    conv_split<<<8000, 256, 0, stream>>>(outw, 512, 0, 512, 0, 1, nullptr, B3L);
    // whh -> quad-interleaved compact [hi|lo]
    conv_splitc<<<2048, 256, 0, stream>>>(whh, 2, WHHC);
    // h0 -> H3[0] compact [hi|lo]
    conv_splitc<<<128, 256, 0, stream>>>(ehs, 0, H3);

    // persistent LSTM v3 (27 steps), slice-spread two-level tree barrier
    zero_bar<<<1, 64, 0, stream>>>(bar);
    lstm_persist3<<<256, 256, 0, stream>>>(H3, WHHC, xg, bar);

    // logits = H3[1:] @ B3L^T + out_b (compact-A remap), scattered to (b, t, v)
    {
        dim3 g(63, 27);
        gemm_bf16_nt<<<g, 256, 0, stream>>>(3456, 8000, 1536,
                                            H3 + (size_t)128 * 1024, 1024, 1, B3L,
                                            outb, nullptr, out, 1);
    }

    argmax_k<<<864, 256, 0, stream>>>(out, out + (size_t)TT * 128 * VV);
}

// Round 12
// 653.701 us; speedup vs baseline: 1.3493x; 1.3493x over previous
//
#include <hip/hip_runtime.h>
#include <math.h>

#define BB 128
#define SS 80
#define HH 512
#define TT 27      // T-1
#define TFULL 28
#define VV 8000

typedef __attribute__((ext_vector_type(4))) float f32x4;
typedef __attribute__((ext_vector_type(8))) short bfrag;

// ---------------- fp32 workspace layout (floats) ----------------
#define OFF_VA   0
#define OFF_VB   512
#define OFF_U    1024
#define OFF_PART 1536
#define OFF_CTX  17920
#define OFF_GB   83456
#define OFF_XG   345600          // 3456*2048 (xg + gb folded)
#define OFF_BAR  7423488         // barrier region (flags + xcd counters)
#define FP32_WS_FLOATS 7489536
// ---------------- bf16 workspace (ushort offsets from bf16 base) ----------------
#define O_H3     0               // 28*128 rows x 1024  [hi|lo] compact split
#define O_WHI    3670016         // 2048 quad rows x 512 (hi)
#define O_WLO    4718592         // 2048 quad rows x 512 (lo)
#define O_R      5767168
#define O_A3X    O_R             // 3456 x 3072
#define O_B3X    (O_R + 10616832)// 2048 x 3072
#define O_B3L    O_R             // 8000 x 1536 (overlays A3X/B3X after xg gemm)

__device__ __forceinline__ unsigned short f2bf(float x) {
    unsigned int u = __float_as_uint(x);
    unsigned int r = (u + 0x7fff + ((u >> 16) & 1)) >> 16;
    return (unsigned short)r;
}
__device__ __forceinline__ float bf2f(unsigned short h) {
    return __uint_as_float(((unsigned int)h) << 16);
}
__device__ __forceinline__ void gload16(void* lds, const void* g) {
    __builtin_amdgcn_global_load_lds(
        (__attribute__((address_space(1))) void*)g,
        (__attribute__((address_space(3))) void*)lds, 16, 0, 0);
}
// sc0 (L1-bypass, L2-served) variant: fresh within-XCD reads without any
// L2 invalidate. (aux bit0 = sc0; aux=17 compiled+ran correctly in R7.)
__device__ __forceinline__ void gload16s(void* lds, const void* g) {
    __builtin_amdgcn_global_load_lds(
        (__attribute__((address_space(1))) void*)g,
        (__attribute__((address_space(3))) void*)lds, 16, 0, 1);
}

__global__ __launch_bounds__(256) void zero_bar(unsigned* b) {
    int i = blockIdx.x * 256 + threadIdx.x;
    if (i < 16512) b[i] = 0u;
}

// ---------- split-bf16 conversion (3K-wide forms, for GEMM operands) ----------
// dst row r (3K wide): A-side: [hi | hi | lo]  B-side: [hi | lo | hi]
// mode 0: src row = r ; mode 1: gather emb row = gidx[(r&127)*28 + (r>>7)]
__global__ __launch_bounds__(256) void conv_split(
    const float* __restrict__ src, int ld, int koff, int K,
    int mode, int bside, const int* __restrict__ gidx,
    unsigned short* __restrict__ dst)
{
    int r = blockIdx.x;
    int sr = r;
    if (mode == 1) { int b = r & 127, t = r >> 7; sr = gidx[b * TFULL + t]; }
    const float* s = src + (size_t)sr * ld + koff;
    unsigned short* d = dst + (size_t)r * (3 * K);
    int off_mid = bside ? 2 * K : K;   // where the duplicated hi goes
    int off_lo  = bside ? K : 2 * K;
    for (int c = threadIdx.x * 4; c < K; c += 1024) {
        float4 v = *(const float4*)(s + c);
        ushort4 hi, lo;
        hi.x = f2bf(v.x); lo.x = f2bf(v.x - bf2f(hi.x));
        hi.y = f2bf(v.y); lo.y = f2bf(v.y - bf2f(hi.y));
        hi.z = f2bf(v.z); lo.z = f2bf(v.z - bf2f(hi.z));
        hi.w = f2bf(v.w); lo.w = f2bf(v.w - bf2f(hi.w));
        *(ushort4*)(d + c) = hi;
        *(ushort4*)(d + off_mid + c) = hi;
        *(ushort4*)(d + off_lo + c) = lo;
    }
}

// compact [hi|lo] split (1024-wide rows of 512 source floats), src row = r
__global__ __launch_bounds__(256) void conv_splitc(
    const float* __restrict__ src, unsigned short* __restrict__ dst)
{
    int r = blockIdx.x;
    const float* s = src + (size_t)r * 512;
    unsigned short* d = dst + (size_t)r * 1024;
    int c = threadIdx.x * 2;
    float2 v = *(const float2*)(s + c);
    unsigned short hx = f2bf(v.x), hy = f2bf(v.y);
    d[c] = hx; d[c + 1] = hy;
    d[512 + c] = f2bf(v.x - bf2f(hx));
    d[512 + c + 1] = f2bf(v.y - bf2f(hy));
}

// whh -> quad-interleaved rows (r -> gate r&3, k r>>2), separate hi / lo arrays
__global__ __launch_bounds__(256) void conv_splitw(
    const float* __restrict__ src,
    unsigned short* __restrict__ whi, unsigned short* __restrict__ wlo)
{
    int r = blockIdx.x;
    int sr = (r & 3) * 512 + (r >> 2);
    const float* s = src + (size_t)sr * 512;
    int c = threadIdx.x * 2;
    float2 v = *(const float2*)(s + c);
    unsigned short hx = f2bf(v.x), hy = f2bf(v.y);
    whi[(size_t)r * 512 + c] = hx;
    whi[(size_t)r * 512 + c + 1] = hy;
    wlo[(size_t)r * 512 + c] = f2bf(v.x - bf2f(hx));
    wlo[(size_t)r * 512 + c + 1] = f2bf(v.y - bf2f(hy));
}

// ---------- bf16 MFMA GEMM: C = A3 @ B3^T (+bias)(+addmat), 128x128 tile, BK=64 ----------
// A3 rows have stride astride; if ahalf, A is compact [hi|lo] (1024) and
// logical k0 maps as eff = k0<512 ? k0 : k0-512 (region1->hi, region2->lo).
// outMode 0: C[m*N+n]   outMode 1: C[((m&127)*27 + (m>>7))*8000 + n]
__global__ __launch_bounds__(256) void gemm_bf16_nt(
    int M, int N, int K3,
    const unsigned short* __restrict__ A3, int astride, int ahalf,
    const unsigned short* __restrict__ B3,
    const float* __restrict__ bias,
    const float* __restrict__ addmat,
    float* __restrict__ C, int outMode)
{
    __shared__ unsigned short Asm[128 * 64];
    __shared__ unsigned short Bsm[128 * 64];
    int tid = threadIdx.x, wave = tid >> 6, lane = tid & 63;

    // ---- block swizzle: XCD-contiguous lid, then GROUP=9 m-fast supertiles ----
    int nT = gridDim.x, mT = gridDim.y;
    int p = blockIdx.y * nT + blockIdx.x;
    int nwg = nT * mT;
    int q = nwg >> 3, rr = nwg & 7;
    int xcd = p & 7, pos = p >> 3;
    int lid = (xcd < rr) ? (xcd * (q + 1) + pos) : (rr * (q + 1) + (xcd - rr) * q + pos);
    const int GROUP = 9;
    int width = GROUP * nT;
    int gid2 = lid / width;
    int first_m = gid2 * GROUP;
    int gsz = mT - first_m; if (gsz > GROUP) gsz = GROUP;
    int rem = lid - gid2 * width;
    int mt = first_m + rem % gsz;
    int nt = rem / gsz;
    int m0 = mt * 128, n0 = nt * 128;

    int wm0 = (wave >> 1) * 64, wn0 = (wave & 1) * 64;
    f32x4 acc[4][4];
    #pragma unroll
    for (int i = 0; i < 4; ++i)
        #pragma unroll
        for (int j = 0; j < 4; ++j) acc[i][j] = (f32x4){0.f, 0.f, 0.f, 0.f};

    int srow8 = lane >> 3;             // row within 8-row chunk
    int schunk = lane & 7;             // 16B chunk within 128B row
    for (int k0 = 0; k0 < K3; k0 += 64) {
        int ek0 = ahalf ? (k0 >= 512 ? k0 - 512 : k0) : k0;
        #pragma unroll
        for (int rep = 0; rep < 4; ++rep) {
            int ci = wave * 4 + rep;
            int row = ci * 8 + srow8;
            int sc = schunk ^ (row & 7);
            int gm = m0 + row; if (gm >= M) gm = M - 1;
            gload16(Asm + ci * 512 + lane * 8,
                    A3 + (size_t)gm * astride + ek0 + sc * 8);
            int gn = n0 + row; if (gn >= N) gn = N - 1;
            gload16(Bsm + ci * 512 + lane * 8,
                    B3 + (size_t)gn * K3 + k0 + sc * 8);
        }
        __syncthreads();
        #pragma unroll
        for (int ks = 0; ks < 2; ++ks) {
            bfrag a[4], b[4];
            #pragma unroll
            for (int i = 0; i < 4; ++i) {
                int ar = wm0 + i * 16 + (lane & 15);
                int ab = (ar * 128 + ks * 64 + (lane >> 4) * 16) ^ ((ar & 7) << 4);
                a[i] = *(const bfrag*)((const char*)Asm + ab);
                int br = wn0 + i * 16 + (lane & 15);
                int bb = (br * 128 + ks * 64 + (lane >> 4) * 16) ^ ((br & 7) << 4);
                b[i] = *(const bfrag*)((const char*)Bsm + bb);
            }
            #pragma unroll
            for (int i = 0; i < 4; ++i)
                #pragma unroll
                for (int j = 0; j < 4; ++j)
                    acc[i][j] = __builtin_amdgcn_mfma_f32_16x16x32_bf16(a[i], b[j], acc[i][j], 0, 0, 0);
        }
        __syncthreads();
    }
    #pragma unroll
    for (int i = 0; i < 4; ++i) {
        #pragma unroll
        for (int r = 0; r < 4; ++r) {
            int m = m0 + wm0 + i * 16 + ((lane >> 4) << 2) + r;
            if (m >= M) continue;
            #pragma unroll
            for (int j = 0; j < 4; ++j) {
                int n = n0 + wn0 + j * 16 + (lane & 15);
                if (n >= N) continue;
                float v = acc[i][j][r];
                if (bias) v += bias[n];
                if (addmat) v += addmat[(size_t)(m & 127) * 2048 + n];
                size_t oi;
                if (outMode == 0) oi = (size_t)m * N + n;
                else { int bb2 = m & 127, tt = m >> 7; oi = ((size_t)bb2 * TT + tt) * (size_t)VV + n; }
                C[oi] = v;
            }
        }
    }
}

// ---------- persistent LSTM v4: XCD-LOCAL h exchange, no global fences ----------
// bg = XCC_ID (8 groups x 16 batch rows); slot = per-XCD atomic (0..31), each
// covering k in [slot*16, slot*16+16) x 4 gates (64 quad rows). All h traffic
// stays in the XCD's shared L2: writes = plain stores (commit at vmcnt retire),
// reads = global_load_lds sc0 (L1-bypass, L2-served). Per-XCD flag barrier,
// no __threadfence / no acquire fence -> no L2 writeback/invalidate per step.
// W-hi slice (64KB) LDS-resident; W-lo read per-lane from cache (read-only).
__global__ __launch_bounds__(256, 1) void lstm_persist4(
    unsigned short* __restrict__ H3,        // 28*128 x 1024 [hi|lo]
    const unsigned short* __restrict__ Whi, // 2048 quad rows x 512 (hi)
    const unsigned short* __restrict__ Wlo, // 2048 quad rows x 512 (lo)
    const float* __restrict__ xgb,          // 3456 x 2048 (xg + gb)
    unsigned* bar)                          // flags: xcd*2048+slot*16 ; ctr: 16384+xcd*16
{
    __shared__ unsigned short Wl[64 * 512];   // 65536 B (W-hi slice)
    __shared__ unsigned short Al[16 * 1024];  // 32768 B (A compact)
    __shared__ int s_ids[2];

    int tid = threadIdx.x, wv = tid >> 6, lane = tid & 63;
    if (tid == 0) {
        unsigned x;
        asm volatile("s_getreg_b32 %0, hwreg(HW_REG_XCC_ID)" : "=s"(x));
        x &= 7u;
        unsigned s = __hip_atomic_fetch_add(bar + 16384 + x * 16, 1u,
                        __ATOMIC_RELAXED, __HIP_MEMORY_SCOPE_AGENT);
        s_ids[0] = (int)x;
        s_ids[1] = (int)(s & 31u);
    }
    __syncthreads();
    int xcd = s_ids[0], slot = s_ids[1];
    int b0 = xcd * 16;              // batch rows [b0, b0+16)
    int nq0 = slot * 64;            // quad rows [nq0, nq0+64)

    int l15 = lane & 15, g4 = (lane >> 4) << 4;
    int arow = l15;                 // A row (m)
    int wr = wv * 16 + l15;         // W-hi LDS row (0..63)
    int n_local = wv * 16 + l15;
    int g = n_local & 3;            // gate
    int kglob = slot * 16 + (n_local >> 2);
    const unsigned short* wloRow = Wlo + (size_t)(nq0 + n_local) * 512;
    float creg[4] = {0.f, 0.f, 0.f, 0.f};

    // stage W-hi slice once: 64 rows x 512 elems (64 x 16B chunks per row)
    {
        const unsigned short* Wsrc = Whi + (size_t)nq0 * 512;
        #pragma unroll
        for (int j = 0; j < 16; ++j) {
            int ci = j * 256 + tid;
            int row = ci >> 6, cc = ci & 63;
            int sc = cc ^ (row & 7);
            gload16(Wl + ci * 8, Wsrc + (size_t)row * 512 + sc * 8);
        }
        asm volatile("s_waitcnt vmcnt(0)" ::: "memory");
    }
    __syncthreads();

    for (int t = 0; t < TT; ++t) {
        // stage A: 16 rows x 1024 elems via sc0 (fresh from own-XCD L2)
        const unsigned short* Asrc = H3 + ((size_t)t * 128 + b0) * 1024;
        #pragma unroll
        for (int j = 0; j < 8; ++j) {
            int ci = j * 256 + tid;
            int row = ci >> 7, cc = ci & 127;
            int sc = cc ^ (row & 7);
            gload16s(Al + ci * 8, Asrc + (size_t)row * 1024 + sc * 8);
        }
        asm volatile("s_waitcnt vmcnt(0)" ::: "memory");
        __syncthreads();

        f32x4 acc0 = (f32x4){0.f, 0.f, 0.f, 0.f};
        f32x4 acc1 = acc0;
        // region 0: a=hi(c), w=hi(c)   [k 0..511]
        #pragma unroll
        for (int c = 0; c < 16; ++c) {
            int ab = (arow * 2048 + c * 64 + g4) ^ ((arow & 7) << 4);
            int wb = (wr * 1024 + c * 64 + g4) ^ ((wr & 7) << 4);
            bfrag a = *(const bfrag*)((const char*)Al + ab);
            bfrag w = *(const bfrag*)((const char*)Wl + wb);
            if (c & 1) acc1 = __builtin_amdgcn_mfma_f32_16x16x32_bf16(a, w, acc1, 0, 0, 0);
            else       acc0 = __builtin_amdgcn_mfma_f32_16x16x32_bf16(a, w, acc0, 0, 0, 0);
        }
        // region 1: a=hi(c), w=lo(c) from global (read-only, cached)
        #pragma unroll
        for (int c = 0; c < 16; ++c) {
            int ab = (arow * 2048 + c * 64 + g4) ^ ((arow & 7) << 4);
            bfrag a = *(const bfrag*)((const char*)Al + ab);
            bfrag w = *(const bfrag*)(wloRow + c * 32 + (lane >> 4) * 8);
            if (c & 1) acc1 = __builtin_amdgcn_mfma_f32_16x16x32_bf16(a, w, acc1, 0, 0, 0);
            else       acc0 = __builtin_amdgcn_mfma_f32_16x16x32_bf16(a, w, acc0, 0, 0, 0);
        }
        // region 2: a=lo(16+c), w=hi(c)
        #pragma unroll
        for (int c = 0; c < 16; ++c) {
            int ab = (arow * 2048 + (16 + c) * 64 + g4) ^ ((arow & 7) << 4);
            int wb = (wr * 1024 + c * 64 + g4) ^ ((wr & 7) << 4);
            bfrag a = *(const bfrag*)((const char*)Al + ab);
            bfrag w = *(const bfrag*)((const char*)Wl + wb);
            if (c & 1) acc1 = __builtin_amdgcn_mfma_f32_16x16x32_bf16(a, w, acc1, 0, 0, 0);
            else       acc0 = __builtin_amdgcn_mfma_f32_16x16x32_bf16(a, w, acc0, 0, 0, 0);
        }
        f32x4 accT = acc0 + acc1;

        // epilogue: xgb add, shfl-down gate gather, LSTM update, compact h write
        #pragma unroll
        for (int r = 0; r < 4; ++r) {
            int m_local = ((lane >> 4) << 2) + r;
            int b = b0 + m_local;
            float v = accT[r] +
                      xgb[(((size_t)t * 128 + b) << 11) + (size_t)g * 512 + kglob];
            float f1 = __shfl_down(v, 1);
            float f2 = __shfl_down(v, 2);
            float f3 = __shfl_down(v, 3);
            if ((lane & 3) == 0) {
                float si = 1.f / (1.f + expf(-v));
                float sf = 1.f / (1.f + expf(-f1));
                float tg = tanhf(f2);
                float so = 1.f / (1.f + expf(-f3));
                float cn = sf * creg[r] + si * tg;
                float hn = so * tanhf(cn);
                creg[r] = cn;
                unsigned short hi = f2bf(hn);
                unsigned short lo = f2bf(hn - bf2f(hi));
                unsigned short* hr = H3 + ((size_t)(t + 1) * 128 + b) * 1024;
                hr[kglob] = hi; hr[512 + kglob] = lo;
            }
        }

        if (t != TT - 1) {
            // XCD-local barrier: stores committed to L2, then flag; 32 threads
            // poll the 32 per-slot flags in parallel. No fences, L2 stays warm.
            asm volatile("s_waitcnt vmcnt(0)" ::: "memory");
            __syncthreads();
            unsigned ph = (unsigned)(t + 1);
            if (tid == 0)
                __hip_atomic_store(bar + xcd * 2048 + slot * 16, ph,
                                   __ATOMIC_RELAXED, __HIP_MEMORY_SCOPE_AGENT);
            if (tid < 32) {
                unsigned* fl = bar + xcd * 2048 + tid * 16;
                while (__hip_atomic_load(fl, __ATOMIC_RELAXED,
                                         __HIP_MEMORY_SCOPE_AGENT) < ph)
                    __builtin_amdgcn_s_sleep(1);
            }
            __syncthreads();
        }
    }
}

// ---------- small helpers ----------
__global__ __launch_bounds__(512) void matvec_col_partial(
    const float* __restrict__ W, int ldw, int koff,
    const float* __restrict__ vin, float* __restrict__ part)
{
    int k = threadIdx.x;
    int o0 = blockIdx.x * 16;
    float acc = 0.f;
    #pragma unroll
    for (int o = 0; o < 16; ++o)
        acc += W[(size_t)(o0 + o) * ldw + koff + k] * vin[o0 + o];
    part[blockIdx.x * 512 + k] = acc;
}

__global__ __launch_bounds__(512) void matvec_combine(
    const float* __restrict__ part, float* __restrict__ vout)
{
    int k = threadIdx.x;
    float s = 0.f;
    #pragma unroll
    for (int c = 0; c < 32; ++c) s += part[c * 512 + k];
    vout[k] = s;
}

__global__ __launch_bounds__(256) void attn_ctx(
    const float* __restrict__ enc, const float* __restrict__ u,
    float* __restrict__ ctx)
{
    __shared__ float su[HH];
    __shared__ float sw[SS];
    __shared__ float ssum;
    int b = blockIdx.x, tid = threadIdx.x;
    su[tid] = u[tid];
    su[tid + 256] = u[tid + 256];
    __syncthreads();
    const float* eb = enc + (size_t)b * SS * HH;
    int wave = tid >> 6, lane = tid & 63;
    for (int s = wave; s < SS; s += 4) {
        const float* row = eb + s * HH;
        float acc = 0.f;
        for (int k = lane; k < HH; k += 64) acc += row[k] * su[k];
        #pragma unroll
        for (int off = 32; off; off >>= 1) acc += __shfl_down(acc, off);
        if (lane == 0) sw[s] = acc;
    }
    __syncthreads();
    if (tid == 0) {
        float mx = sw[0];
        for (int s = 1; s < SS; ++s) mx = fmaxf(mx, sw[s]);
        float sum = 0.f;
        for (int s = 0; s < SS; ++s) { float e = expf(sw[s] - mx); sw[s] = e; sum += e; }
        ssum = sum;
    }
    __syncthreads();
    float inv = 1.0f / ssum;
    for (int k = tid; k < HH; k += 256) {
        float acc = 0.f;
        #pragma unroll 4
        for (int s = 0; s < SS; ++s) acc += sw[s] * eb[s * HH + k];
        ctx[(size_t)b * HH + k] = acc * inv;
    }
}

// fp32 vector GEMM, kept only for gbase (ctx @ Wc^T + b_ih + b_hh)
__global__ __launch_bounds__(256) void gemm_nt(
    int M, int N, int K,
    const float* __restrict__ A, int lda,
    const float* __restrict__ Bm, int ldb, int kob,
    const float* __restrict__ bias1, const float* __restrict__ bias2,
    float* __restrict__ C)
{
    __shared__ float As[16][132];
    __shared__ float Bs[16][132];
    int tid = threadIdx.x;
    int m0 = blockIdx.y * 128, n0 = blockIdx.x * 128;
    int tn = tid & 15, tm = tid >> 4;
    float acc[8][8];
    #pragma unroll
    for (int i = 0; i < 8; ++i)
        #pragma unroll
        for (int j = 0; j < 8; ++j) acc[i][j] = 0.f;
    int lr = tid >> 2;
    int lk = (tid & 3) * 4;
    for (int k0 = 0; k0 < K; k0 += 16) {
        #pragma unroll
        for (int half = 0; half < 2; ++half) {
            int mr = lr + half * 64;
            int m = m0 + mr;
            float4 va = make_float4(0.f, 0.f, 0.f, 0.f);
            if (m < M) va = *(const float4*)(A + (size_t)m * lda + k0 + lk);
            As[lk + 0][mr] = va.x; As[lk + 1][mr] = va.y;
            As[lk + 2][mr] = va.z; As[lk + 3][mr] = va.w;
            int n = n0 + mr;
            float4 vb = make_float4(0.f, 0.f, 0.f, 0.f);
            if (n < N) vb = *(const float4*)(Bm + (size_t)n * ldb + kob + k0 + lk);
            Bs[lk + 0][mr] = vb.x; Bs[lk + 1][mr] = vb.y;
            Bs[lk + 2][mr] = vb.z; Bs[lk + 3][mr] = vb.w;
        }
        __syncthreads();
        #pragma unroll
        for (int kk = 0; kk < 16; ++kk) {
            float4 a0 = *(const float4*)&As[kk][tm * 8];
            float4 a1 = *(const float4*)&As[kk][tm * 8 + 4];
            float4 b0 = *(const float4*)&Bs[kk][tn * 8];
            float4 b1 = *(const float4*)&Bs[kk][tn * 8 + 4];
            float av[8] = {a0.x, a0.y, a0.z, a0.w, a1.x, a1.y, a1.z, a1.w};
            float bv[8] = {b0.x, b0.y, b0.z, b0.w, b1.x, b1.y, b1.z, b1.w};
            #pragma unroll
            for (int i = 0; i < 8; ++i)
                #pragma unroll
                for (int j = 0; j < 8; ++j)
                    acc[i][j] += av[i] * bv[j];
        }
        __syncthreads();
    }
    #pragma unroll
    for (int i = 0; i < 8; ++i) {
        int m = m0 + tm * 8 + i;
        if (m >= M) continue;
        #pragma unroll
        for (int j = 0; j < 8; ++j) {
            int n = n0 + tn * 8 + j;
            if (n >= N) continue;
            float v = acc[i][j];
            if (bias1) v += bias1[n];
            if (bias2) v += bias2[n];
            C[(size_t)m * N + n] = v;
        }
    }
}

__global__ __launch_bounds__(256) void argmax_k(
    const float* __restrict__ logits, float* __restrict__ preds)
{
    int r = blockIdx.x * 4 + (threadIdx.x >> 6);
    int lane = threadIdx.x & 63;
    const float* row = logits + (size_t)r * VV;
    float best = -INFINITY;
    int bi = 0;
    for (int v = lane; v < VV; v += 64) {
        float x = row[v];
        if (x > best) { best = x; bi = v; }
    }
    #pragma unroll
    for (int off = 32; off; off >>= 1) {
        float ob = __shfl_down(best, off);
        int oi = __shfl_down(bi, off);
        if (ob > best || (ob == best && oi < bi)) { best = ob; bi = oi; }
    }
    if (lane == 0) preds[r] = (float)bi;
}

extern "C" void kernel_launch(void* const* d_in, const int* in_sizes, int n_in,
                              void* d_out, int out_size, void* d_ws, size_t ws_size,
                              hipStream_t stream) {
    const float* ehs   = (const float*)d_in[0];
    const float* enc   = (const float*)d_in[1];
    const int*   tgt   = (const int*)d_in[2];
    const float* emb   = (const float*)d_in[4];
    const float* fc1w  = (const float*)d_in[5];
    const float* fc2w  = (const float*)d_in[7];
    const float* fc3w  = (const float*)d_in[9];
    const float* fc4w  = (const float*)d_in[11];
    const float* attnw = (const float*)d_in[13];
    const float* wih   = (const float*)d_in[14];
    const float* whh   = (const float*)d_in[15];
    const float* bih   = (const float*)d_in[16];
    const float* bhh   = (const float*)d_in[17];
    const float* outw  = (const float*)d_in[18];
    const float* outb  = (const float*)d_in[19];
    float* out = (float*)d_out;
    float* ws  = (float*)d_ws;

    float* vA   = ws + OFF_VA;
    float* vB   = ws + OFF_VB;
    float* u    = ws + OFF_U;
    float* part = ws + OFF_PART;
    float* ctx  = ws + OFF_CTX;
    float* gb   = ws + OFF_GB;
    float* xg   = ws + OFF_XG;
    unsigned* bar = (unsigned*)(ws + OFF_BAR);
    unsigned short* bfb = (unsigned short*)(ws + FP32_WS_FLOATS);
    unsigned short* H3   = bfb + O_H3;
    unsigned short* WHI  = bfb + O_WHI;
    unsigned short* WLO  = bfb + O_WLO;
    unsigned short* A3X  = bfb + O_A3X;
    unsigned short* B3X  = bfb + O_B3X;
    unsigned short* B3L  = bfb + O_B3L;

    // u = W1e^T W2^T W3^T W4^T attn_w
    matvec_col_partial<<<32, 512, 0, stream>>>(fc4w, 512, 0, attnw, part);
    matvec_combine<<<1, 512, 0, stream>>>(part, vA);
    matvec_col_partial<<<32, 512, 0, stream>>>(fc3w, 512, 0, vA, part);
    matvec_combine<<<1, 512, 0, stream>>>(part, vB);
    matvec_col_partial<<<32, 512, 0, stream>>>(fc2w, 512, 0, vB, part);
    matvec_combine<<<1, 512, 0, stream>>>(part, vA);
    matvec_col_partial<<<32, 512, 0, stream>>>(fc1w, 1024, 0, vA, part);
    matvec_combine<<<1, 512, 0, stream>>>(part, u);

    attn_ctx<<<128, 256, 0, stream>>>(enc, u, ctx);

    // gbase = ctx @ Wc^T + b_ih + b_hh  (fp32 path, tiny)
    {
        dim3 g(16, 1);
        gemm_nt<<<g, 256, 0, stream>>>(128, 2048, 512, ctx, 512,
                                       wih, 1536, 1024, bih, bhh, gb);
    }

    // xgb = gather(emb, tgt) @ Wx^T + gb  via split-bf16 MFMA
    conv_split<<<2048, 256, 0, stream>>>(wih, 1536, 0, 1024, 0, 1, nullptr, B3X);
    conv_split<<<3456, 256, 0, stream>>>(emb, 1024, 0, 1024, 1, 0, tgt, A3X);
    {
        dim3 g(16, 27);
        gemm_bf16_nt<<<g, 256, 0, stream>>>(3456, 2048, 3072, A3X, 3072, 0, B3X,
                                            nullptr, gb, xg, 0);
    }

    // B3L overlays A3X/B3X — only after the xg gemm
    conv_split<<<8000, 256, 0, stream>>>(outw, 512, 0, 512, 0, 1, nullptr, B3L);
    // whh -> quad-interleaved hi/lo arrays
    conv_splitw<<<2048, 256, 0, stream>>>(whh, WHI, WLO);
    // h0 -> H3[0] compact [hi|lo]
    conv_splitc<<<128, 256, 0, stream>>>(ehs, H3);

    // persistent LSTM v4 (27 steps), XCD-local exchange + per-XCD flag barrier
    zero_bar<<<65, 256, 0, stream>>>(bar);
    lstm_persist4<<<256, 256, 0, stream>>>(H3, WHI, WLO, xg, bar);

    // logits = H3[1:] @ B3L^T + out_b (compact-A remap), scattered to (b, t, v)
    {
        dim3 g(63, 27);
        gemm_bf16_nt<<<g, 256, 0, stream>>>(3456, 8000, 1536,
                                            H3 + (size_t)128 * 1024, 1024, 1, B3L,
                                            outb, nullptr, out, 1);
    }

    argmax_k<<<864, 256, 0, stream>>>(out, out + (size_t)TT * 128 * VV);
}

// Round 13
// 623.253 us; speedup vs baseline: 1.4153x; 1.0489x over previous
//
#include <hip/hip_runtime.h>
#include <math.h>

#define BB 128
#define SS 80
#define HH 512
#define TT 27      // T-1
#define TFULL 28
#define VV 8000

typedef __attribute__((ext_vector_type(4))) float f32x4;
typedef __attribute__((ext_vector_type(8))) short bfrag;

// ---------------- fp32 workspace layout (floats) ----------------
#define OFF_VA   0
#define OFF_VB   512
#define OFF_U    1024
#define OFF_PART 1536
#define OFF_CTX  17920
#define OFF_GB   83456
#define OFF_XG   345600          // 3456*2048 (xg + gb folded)
#define OFF_BAR  7423488         // barrier region (flags + xcd counters)
#define FP32_WS_FLOATS 7489536
// ---------------- bf16 workspace (ushort offsets from bf16 base) ----------------
#define O_H3     0               // 28*128 rows x 1024  [hi|lo] compact split
#define O_WHI    3670016         // 2048 quad rows x 512 (hi)
#define O_WLO    4718592         // 2048 quad rows x 512 (lo)
#define O_R      5767168
#define O_A3X    O_R             // 3456 x 3072
#define O_B3X    (O_R + 10616832)// 2048 x 3072
#define O_B3L    O_R             // 8000 x 1536 (overlays A3X/B3X after xg gemm)

__device__ __forceinline__ unsigned short f2bf(float x) {
    unsigned int u = __float_as_uint(x);
    unsigned int r = (u + 0x7fff + ((u >> 16) & 1)) >> 16;
    return (unsigned short)r;
}
__device__ __forceinline__ float bf2f(unsigned short h) {
    return __uint_as_float(((unsigned int)h) << 16);
}
__device__ __forceinline__ void gload16(void* lds, const void* g) {
    __builtin_amdgcn_global_load_lds(
        (__attribute__((address_space(1))) void*)g,
        (__attribute__((address_space(3))) void*)lds, 16, 0, 0);
}
// sc0 (L1-bypass, L2-served): fresh within-XCD reads, no invalidate
__device__ __forceinline__ void gload16s(void* lds, const void* g) {
    __builtin_amdgcn_global_load_lds(
        (__attribute__((address_space(1))) void*)g,
        (__attribute__((address_space(3))) void*)lds, 16, 0, 1);
}

__global__ __launch_bounds__(256) void zero_bar(unsigned* b) {
    int i = blockIdx.x * 256 + threadIdx.x;
    if (i < 16512) b[i] = 0u;
}

// ---------- split-bf16 conversion (3K-wide forms, for GEMM operands) ----------
// dst row r (3K wide): A-side: [hi | hi | lo]  B-side: [hi | lo | hi]
// mode 0: src row = r ; mode 1: gather emb row = gidx[(r&127)*28 + (r>>7)]
__global__ __launch_bounds__(256) void conv_split(
    const float* __restrict__ src, int ld, int koff, int K,
    int mode, int bside, const int* __restrict__ gidx,
    unsigned short* __restrict__ dst)
{
    int r = blockIdx.x;
    int sr = r;
    if (mode == 1) { int b = r & 127, t = r >> 7; sr = gidx[b * TFULL + t]; }
    const float* s = src + (size_t)sr * ld + koff;
    unsigned short* d = dst + (size_t)r * (3 * K);
    int off_mid = bside ? 2 * K : K;   // where the duplicated hi goes
    int off_lo  = bside ? K : 2 * K;
    for (int c = threadIdx.x * 4; c < K; c += 1024) {
        float4 v = *(const float4*)(s + c);
        ushort4 hi, lo;
        hi.x = f2bf(v.x); lo.x = f2bf(v.x - bf2f(hi.x));
        hi.y = f2bf(v.y); lo.y = f2bf(v.y - bf2f(hi.y));
        hi.z = f2bf(v.z); lo.z = f2bf(v.z - bf2f(hi.z));
        hi.w = f2bf(v.w); lo.w = f2bf(v.w - bf2f(hi.w));
        *(ushort4*)(d + c) = hi;
        *(ushort4*)(d + off_mid + c) = hi;
        *(ushort4*)(d + off_lo + c) = lo;
    }
}

// compact [hi|lo] split (1024-wide rows of 512 source floats), src row = r
__global__ __launch_bounds__(256) void conv_splitc(
    const float* __restrict__ src, unsigned short* __restrict__ dst)
{
    int r = blockIdx.x;
    const float* s = src + (size_t)r * 512;
    unsigned short* d = dst + (size_t)r * 1024;
    int c = threadIdx.x * 2;
    float2 v = *(const float2*)(s + c);
    unsigned short hx = f2bf(v.x), hy = f2bf(v.y);
    d[c] = hx; d[c + 1] = hy;
    d[512 + c] = f2bf(v.x - bf2f(hx));
    d[512 + c + 1] = f2bf(v.y - bf2f(hy));
}

// whh -> quad-interleaved rows (r -> gate r&3, k r>>2), separate hi / lo arrays
__global__ __launch_bounds__(256) void conv_splitw(
    const float* __restrict__ src,
    unsigned short* __restrict__ whi, unsigned short* __restrict__ wlo)
{
    int r = blockIdx.x;
    int sr = (r & 3) * 512 + (r >> 2);
    const float* s = src + (size_t)sr * 512;
    int c = threadIdx.x * 2;
    float2 v = *(const float2*)(s + c);
    unsigned short hx = f2bf(v.x), hy = f2bf(v.y);
    whi[(size_t)r * 512 + c] = hx;
    whi[(size_t)r * 512 + c + 1] = hy;
    wlo[(size_t)r * 512 + c] = f2bf(v.x - bf2f(hx));
    wlo[(size_t)r * 512 + c + 1] = f2bf(v.y - bf2f(hy));
}

// ---------- bf16 MFMA GEMM v2: dbuf LDS + counted vmcnt (T3 2-phase) ----------
// C = A3 @ B3^T (+bias)(+addmat), 128x128 tile, BK=64, 2-deep pipeline.
// Per wave per K-step: 8 gload_lds -> wait vmcnt(8) keeps next tile in flight.
// Raw s_barrier (NOT __syncthreads: that drains vmcnt(0) and kills overlap).
// A3 rows stride astride; if ahalf, A compact [hi|lo]: eff k0 = k0<512?k0:k0-512.
// outMode 0: C[m*N+n]   outMode 1: C[((m&127)*27 + (m>>7))*8000 + n]
__global__ __launch_bounds__(256) void gemm_bf16_nt(
    int M, int N, int K3,
    const unsigned short* __restrict__ A3, int astride, int ahalf,
    const unsigned short* __restrict__ B3,
    const float* __restrict__ bias,
    const float* __restrict__ addmat,
    float* __restrict__ C, int outMode)
{
    __shared__ unsigned short Asm[2][128 * 64];
    __shared__ unsigned short Bsm[2][128 * 64];
    int tid = threadIdx.x, wave = tid >> 6, lane = tid & 63;

    // ---- block swizzle: XCD-contiguous lid, then GROUP=9 m-fast supertiles ----
    int nT = gridDim.x, mT = gridDim.y;
    int p = blockIdx.y * nT + blockIdx.x;
    int nwg = nT * mT;
    int q = nwg >> 3, rr = nwg & 7;
    int xcd = p & 7, pos = p >> 3;
    int lid = (xcd < rr) ? (xcd * (q + 1) + pos) : (rr * (q + 1) + (xcd - rr) * q + pos);
    const int GROUP = 9;
    int width = GROUP * nT;
    int gid2 = lid / width;
    int first_m = gid2 * GROUP;
    int gsz = mT - first_m; if (gsz > GROUP) gsz = GROUP;
    int rem = lid - gid2 * width;
    int mt = first_m + rem % gsz;
    int nt = rem / gsz;
    int m0 = mt * 128, n0 = nt * 128;

    int wm0 = (wave >> 1) * 64, wn0 = (wave & 1) * 64;
    f32x4 acc[4][4];
    #pragma unroll
    for (int i = 0; i < 4; ++i)
        #pragma unroll
        for (int j = 0; j < 4; ++j) acc[i][j] = (f32x4){0.f, 0.f, 0.f, 0.f};

    int srow8 = lane >> 3;             // row within 8-row chunk
    int schunk = lane & 7;             // 16B chunk within 128B row

    auto STAGE = [&](int buf, int k0) {
        int ek0 = ahalf ? (k0 >= 512 ? k0 - 512 : k0) : k0;
        #pragma unroll
        for (int rep = 0; rep < 4; ++rep) {
            int ci = wave * 4 + rep;
            int row = ci * 8 + srow8;
            int sc = schunk ^ (row & 7);
            int gm = m0 + row; if (gm >= M) gm = M - 1;
            gload16(Asm[buf] + ci * 512 + lane * 8,
                    A3 + (size_t)gm * astride + ek0 + sc * 8);
            int gn = n0 + row; if (gn >= N) gn = N - 1;
            gload16(Bsm[buf] + ci * 512 + lane * 8,
                    B3 + (size_t)gn * K3 + k0 + sc * 8);
        }
    };

    int nK = K3 >> 6;
    STAGE(0, 0);
    STAGE(1, 64);
    for (int kc = 0; kc < nK; ++kc) {
        if (kc < nK - 1) asm volatile("s_waitcnt vmcnt(8)" ::: "memory");
        else             asm volatile("s_waitcnt vmcnt(0)" ::: "memory");
        __builtin_amdgcn_s_barrier();
        const unsigned short* Ab = Asm[kc & 1];
        const unsigned short* Bb = Bsm[kc & 1];
        #pragma unroll
        for (int ks = 0; ks < 2; ++ks) {
            bfrag a[4], b[4];
            #pragma unroll
            for (int i = 0; i < 4; ++i) {
                int ar = wm0 + i * 16 + (lane & 15);
                int ab = (ar * 128 + ks * 64 + (lane >> 4) * 16) ^ ((ar & 7) << 4);
                a[i] = *(const bfrag*)((const char*)Ab + ab);
                int br = wn0 + i * 16 + (lane & 15);
                int bb = (br * 128 + ks * 64 + (lane >> 4) * 16) ^ ((br & 7) << 4);
                b[i] = *(const bfrag*)((const char*)Bb + bb);
            }
            #pragma unroll
            for (int i = 0; i < 4; ++i)
                #pragma unroll
                for (int j = 0; j < 4; ++j)
                    acc[i][j] = __builtin_amdgcn_mfma_f32_16x16x32_bf16(a[i], b[j], acc[i][j], 0, 0, 0);
        }
        __builtin_amdgcn_s_barrier();
        if (kc + 2 < nK) STAGE(kc & 1, (kc + 2) * 64);
    }
    #pragma unroll
    for (int i = 0; i < 4; ++i) {
        #pragma unroll
        for (int r = 0; r < 4; ++r) {
            int m = m0 + wm0 + i * 16 + ((lane >> 4) << 2) + r;
            if (m >= M) continue;
            #pragma unroll
            for (int j = 0; j < 4; ++j) {
                int n = n0 + wn0 + j * 16 + (lane & 15);
                if (n >= N) continue;
                float v = acc[i][j][r];
                if (bias) v += bias[n];
                if (addmat) v += addmat[(size_t)(m & 127) * 2048 + n];
                size_t oi;
                if (outMode == 0) oi = (size_t)m * N + n;
                else { int bb2 = m & 127, tt = m >> 7; oi = ((size_t)bb2 * TT + tt) * (size_t)VV + n; }
                __builtin_nontemporal_store(v, &C[oi]);   // keep L2 clean for B-panels
            }
        }
    }
}

// ---------- persistent LSTM v4: XCD-LOCAL h exchange (R12-proven) + xgb prefetch ----------
__global__ __launch_bounds__(256, 1) void lstm_persist4(
    unsigned short* __restrict__ H3,        // 28*128 x 1024 [hi|lo]
    const unsigned short* __restrict__ Whi, // 2048 quad rows x 512 (hi)
    const unsigned short* __restrict__ Wlo, // 2048 quad rows x 512 (lo)
    const float* __restrict__ xgb,          // 3456 x 2048 (xg + gb)
    unsigned* bar)                          // flags: xcd*2048+slot*16 ; ctr: 16384+xcd*16
{
    __shared__ unsigned short Wl[64 * 512];   // 65536 B (W-hi slice)
    __shared__ unsigned short Al[16 * 1024];  // 32768 B (A compact)
    __shared__ int s_ids[2];

    int tid = threadIdx.x, wv = tid >> 6, lane = tid & 63;
    if (tid == 0) {
        unsigned x;
        asm volatile("s_getreg_b32 %0, hwreg(HW_REG_XCC_ID)" : "=s"(x));
        x &= 7u;
        unsigned s = __hip_atomic_fetch_add(bar + 16384 + x * 16, 1u,
                        __ATOMIC_RELAXED, __HIP_MEMORY_SCOPE_AGENT);
        s_ids[0] = (int)x;
        s_ids[1] = (int)(s & 31u);
    }
    __syncthreads();
    int xcd = s_ids[0], slot = s_ids[1];
    int b0 = xcd * 16;              // batch rows [b0, b0+16)
    int nq0 = slot * 64;            // quad rows [nq0, nq0+64)

    int l15 = lane & 15, g4 = (lane >> 4) << 4;
    int arow = l15;                 // A row (m)
    int wr = wv * 16 + l15;         // W-hi LDS row (0..63)
    int n_local = wv * 16 + l15;
    int g = n_local & 3;            // gate
    int kglob = slot * 16 + (n_local >> 2);
    const unsigned short* wloRow = Wlo + (size_t)(nq0 + n_local) * 512;
    float creg[4] = {0.f, 0.f, 0.f, 0.f};

    // stage W-hi slice once: 64 rows x 512 elems (64 x 16B chunks per row)
    {
        const unsigned short* Wsrc = Whi + (size_t)nq0 * 512;
        #pragma unroll
        for (int j = 0; j < 16; ++j) {
            int ci = j * 256 + tid;
            int row = ci >> 6, cc = ci & 63;
            int sc = cc ^ (row & 7);
            gload16(Wl + ci * 8, Wsrc + (size_t)row * 512 + sc * 8);
        }
        asm volatile("s_waitcnt vmcnt(0)" ::: "memory");
    }
    __syncthreads();

    for (int t = 0; t < TT; ++t) {
        // stage A: 16 rows x 1024 elems via sc0 (fresh from own-XCD L2)
        const unsigned short* Asrc = H3 + ((size_t)t * 128 + b0) * 1024;
        #pragma unroll
        for (int j = 0; j < 8; ++j) {
            int ci = j * 256 + tid;
            int row = ci >> 7, cc = ci & 127;
            int sc = cc ^ (row & 7);
            gload16s(Al + ci * 8, Asrc + (size_t)row * 1024 + sc * 8);
        }
        // prefetch epilogue xgb values; counted vmcnt leaves them in flight
        float xpre[4];
        #pragma unroll
        for (int r = 0; r < 4; ++r) {
            int m_local = ((lane >> 4) << 2) + r;
            xpre[r] = xgb[(((size_t)t * 128 + b0 + m_local) << 11) + (size_t)g * 512 + kglob];
        }
        asm volatile("s_waitcnt vmcnt(4)" ::: "memory");   // A-stage (8) done; 4 xpre in flight
        __builtin_amdgcn_s_barrier();

        f32x4 acc0 = (f32x4){0.f, 0.f, 0.f, 0.f};
        f32x4 acc1 = acc0;
        // region 0: a=hi(c), w=hi(c)   [k 0..511]
        #pragma unroll
        for (int c = 0; c < 16; ++c) {
            int ab = (arow * 2048 + c * 64 + g4) ^ ((arow & 7) << 4);
            int wb = (wr * 1024 + c * 64 + g4) ^ ((wr & 7) << 4);
            bfrag a = *(const bfrag*)((const char*)Al + ab);
            bfrag w = *(const bfrag*)((const char*)Wl + wb);
            if (c & 1) acc1 = __builtin_amdgcn_mfma_f32_16x16x32_bf16(a, w, acc1, 0, 0, 0);
            else       acc0 = __builtin_amdgcn_mfma_f32_16x16x32_bf16(a, w, acc0, 0, 0, 0);
        }
        // region 1: a=hi(c), w=lo(c) from global (read-only, cached)
        #pragma unroll
        for (int c = 0; c < 16; ++c) {
            int ab = (arow * 2048 + c * 64 + g4) ^ ((arow & 7) << 4);
            bfrag a = *(const bfrag*)((const char*)Al + ab);
            bfrag w = *(const bfrag*)(wloRow + c * 32 + (lane >> 4) * 8);
            if (c & 1) acc1 = __builtin_amdgcn_mfma_f32_16x16x32_bf16(a, w, acc1, 0, 0, 0);
            else       acc0 = __builtin_amdgcn_mfma_f32_16x16x32_bf16(a, w, acc0, 0, 0, 0);
        }
        // region 2: a=lo(16+c), w=hi(c)
        #pragma unroll
        for (int c = 0; c < 16; ++c) {
            int ab = (arow * 2048 + (16 + c) * 64 + g4) ^ ((arow & 7) << 4);
            int wb = (wr * 1024 + c * 64 + g4) ^ ((wr & 7) << 4);
            bfrag a = *(const bfrag*)((const char*)Al + ab);
            bfrag w = *(const bfrag*)((const char*)Wl + wb);
            if (c & 1) acc1 = __builtin_amdgcn_mfma_f32_16x16x32_bf16(a, w, acc1, 0, 0, 0);
            else       acc0 = __builtin_amdgcn_mfma_f32_16x16x32_bf16(a, w, acc0, 0, 0, 0);
        }
        f32x4 accT = acc0 + acc1;

        // epilogue: xpre add, shfl-down gate gather, LSTM update, compact h write
        #pragma unroll
        for (int r = 0; r < 4; ++r) {
            int m_local = ((lane >> 4) << 2) + r;
            int b = b0 + m_local;
            float v = accT[r] + xpre[r];
            float f1 = __shfl_down(v, 1);
            float f2 = __shfl_down(v, 2);
            float f3 = __shfl_down(v, 3);
            if ((lane & 3) == 0) {
                float si = 1.f / (1.f + expf(-v));
                float sf = 1.f / (1.f + expf(-f1));
                float tg = tanhf(f2);
                float so = 1.f / (1.f + expf(-f3));
                float cn = sf * creg[r] + si * tg;
                float hn = so * tanhf(cn);
                creg[r] = cn;
                unsigned short hi = f2bf(hn);
                unsigned short lo = f2bf(hn - bf2f(hi));
                unsigned short* hr = H3 + ((size_t)(t + 1) * 128 + b) * 1024;
                hr[kglob] = hi; hr[512 + kglob] = lo;
            }
        }

        if (t != TT - 1) {
            // XCD-local barrier: stores committed to L2, then flag; 32 threads
            // poll the 32 per-slot flags in parallel. No fences, L2 stays warm.
            asm volatile("s_waitcnt vmcnt(0)" ::: "memory");
            __syncthreads();
            unsigned ph = (unsigned)(t + 1);
            if (tid == 0)
                __hip_atomic_store(bar + xcd * 2048 + slot * 16, ph,
                                   __ATOMIC_RELAXED, __HIP_MEMORY_SCOPE_AGENT);
            if (tid < 32) {
                unsigned* fl = bar + xcd * 2048 + tid * 16;
                while (__hip_atomic_load(fl, __ATOMIC_RELAXED,
                                         __HIP_MEMORY_SCOPE_AGENT) < ph)
                    __builtin_amdgcn_s_sleep(1);
            }
            __syncthreads();
        }
    }
}

// ---------- small helpers ----------
__global__ __launch_bounds__(512) void matvec_col_partial(
    const float* __restrict__ W, int ldw, int koff,
    const float* __restrict__ vin, float* __restrict__ part)
{
    int k = threadIdx.x;
    int o0 = blockIdx.x * 16;
    float acc = 0.f;
    #pragma unroll
    for (int o = 0; o < 16; ++o)
        acc += W[(size_t)(o0 + o) * ldw + koff + k] * vin[o0 + o];
    part[blockIdx.x * 512 + k] = acc;
}

__global__ __launch_bounds__(512) void matvec_combine(
    const float* __restrict__ part, float* __restrict__ vout)
{
    int k = threadIdx.x;
    float s = 0.f;
    #pragma unroll
    for (int c = 0; c < 32; ++c) s += part[c * 512 + k];
    vout[k] = s;
}

__global__ __launch_bounds__(256) void attn_ctx(
    const float* __restrict__ enc, const float* __restrict__ u,
    float* __restrict__ ctx)
{
    __shared__ float su[HH];
    __shared__ float sw[SS];
    __shared__ float ssum;
    int b = blockIdx.x, tid = threadIdx.x;
    su[tid] = u[tid];
    su[tid + 256] = u[tid + 256];
    __syncthreads();
    const float* eb = enc + (size_t)b * SS * HH;
    int wave = tid >> 6, lane = tid & 63;
    for (int s = wave; s < SS; s += 4) {
        const float* row = eb + s * HH;
        float acc = 0.f;
        for (int k = lane; k < HH; k += 64) acc += row[k] * su[k];
        #pragma unroll
        for (int off = 32; off; off >>= 1) acc += __shfl_down(acc, off);
        if (lane == 0) sw[s] = acc;
    }
    __syncthreads();
    if (tid == 0) {
        float mx = sw[0];
        for (int s = 1; s < SS; ++s) mx = fmaxf(mx, sw[s]);
        float sum = 0.f;
        for (int s = 0; s < SS; ++s) { float e = expf(sw[s] - mx); sw[s] = e; sum += e; }
        ssum = sum;
    }
    __syncthreads();
    float inv = 1.0f / ssum;
    for (int k = tid; k < HH; k += 256) {
        float acc = 0.f;
        #pragma unroll 4
        for (int s = 0; s < SS; ++s) acc += sw[s] * eb[s * HH + k];
        ctx[(size_t)b * HH + k] = acc * inv;
    }
}

// fp32 vector GEMM, kept only for gbase (ctx @ Wc^T + b_ih + b_hh)
__global__ __launch_bounds__(256) void gemm_nt(
    int M, int N, int K,
    const float* __restrict__ A, int lda,
    const float* __restrict__ Bm, int ldb, int kob,
    const float* __restrict__ bias1, const float* __restrict__ bias2,
    float* __restrict__ C)
{
    __shared__ float As[16][132];
    __shared__ float Bs[16][132];
    int tid = threadIdx.x;
    int m0 = blockIdx.y * 128, n0 = blockIdx.x * 128;
    int tn = tid & 15, tm = tid >> 4;
    float acc[8][8];
    #pragma unroll
    for (int i = 0; i < 8; ++i)
        #pragma unroll
        for (int j = 0; j < 8; ++j) acc[i][j] = 0.f;
    int lr = tid >> 2;
    int lk = (tid & 3) * 4;
    for (int k0 = 0; k0 < K; k0 += 16) {
        #pragma unroll
        for (int half = 0; half < 2; ++half) {
            int mr = lr + half * 64;
            int m = m0 + mr;
            float4 va = make_float4(0.f, 0.f, 0.f, 0.f);
            if (m < M) va = *(const float4*)(A + (size_t)m * lda + k0 + lk);
            As[lk + 0][mr] = va.x; As[lk + 1][mr] = va.y;
            As[lk + 2][mr] = va.z; As[lk + 3][mr] = va.w;
            int n = n0 + mr;
            float4 vb = make_float4(0.f, 0.f, 0.f, 0.f);
            if (n < N) vb = *(const float4*)(Bm + (size_t)n * ldb + kob + k0 + lk);
            Bs[lk + 0][mr] = vb.x; Bs[lk + 1][mr] = vb.y;
            Bs[lk + 2][mr] = vb.z; Bs[lk + 3][mr] = vb.w;
        }
        __syncthreads();
        #pragma unroll
        for (int kk = 0; kk < 16; ++kk) {
            float4 a0 = *(const float4*)&As[kk][tm * 8];
            float4 a1 = *(const float4*)&As[kk][tm * 8 + 4];
            float4 b0 = *(const float4*)&Bs[kk][tn * 8];
            float4 b1 = *(const float4*)&Bs[kk][tn * 8 + 4];
            float av[8] = {a0.x, a0.y, a0.z, a0.w, a1.x, a1.y, a1.z, a1.w};
            float bv[8] = {b0.x, b0.y, b0.z, b0.w, b1.x, b1.y, b1.z, b1.w};
            #pragma unroll
            for (int i = 0; i < 8; ++i)
                #pragma unroll
                for (int j = 0; j < 8; ++j)
                    acc[i][j] += av[i] * bv[j];
        }
        __syncthreads();
    }
    #pragma unroll
    for (int i = 0; i < 8; ++i) {
        int m = m0 + tm * 8 + i;
        if (m >= M) continue;
        #pragma unroll
        for (int j = 0; j < 8; ++j) {
            int n = n0 + tn * 8 + j;
            if (n >= N) continue;
            float v = acc[i][j];
            if (bias1) v += bias1[n];
            if (bias2) v += bias2[n];
            C[(size_t)m * N + n] = v;
        }
    }
}

__global__ __launch_bounds__(256) void argmax_k(
    const float* __restrict__ logits, float* __restrict__ preds)
{
    int r = blockIdx.x * 4 + (threadIdx.x >> 6);
    int lane = threadIdx.x & 63;
    const float* row = logits + (size_t)r * VV;
    float best = -INFINITY;
    int bi = 0;
    for (int v = lane; v < VV; v += 64) {
        float x = row[v];
        if (x > best) { best = x; bi = v; }
    }
    #pragma unroll
    for (int off = 32; off; off >>= 1) {
        float ob = __shfl_down(best, off);
        int oi = __shfl_down(bi, off);
        if (ob > best || (ob == best && oi < bi)) { best = ob; bi = oi; }
    }
    if (lane == 0) preds[r] = (float)bi;
}

extern "C" void kernel_launch(void* const* d_in, const int* in_sizes, int n_in,
                              void* d_out, int out_size, void* d_ws, size_t ws_size,
                              hipStream_t stream) {
    const float* ehs   = (const float*)d_in[0];
    const float* enc   = (const float*)d_in[1];
    const int*   tgt   = (const int*)d_in[2];
    const float* emb   = (const float*)d_in[4];
    const float* fc1w  = (const float*)d_in[5];
    const float* fc2w  = (const float*)d_in[7];
    const float* fc3w  = (const float*)d_in[9];
    const float* fc4w  = (const float*)d_in[11];
    const float* attnw = (const float*)d_in[13];
    const float* wih   = (const float*)d_in[14];
    const float* whh   = (const float*)d_in[15];
    const float* bih   = (const float*)d_in[16];
    const float* bhh   = (const float*)d_in[17];
    const float* outw  = (const float*)d_in[18];
    const float* outb  = (const float*)d_in[19];
    float* out = (float*)d_out;
    float* ws  = (float*)d_ws;

    float* vA   = ws + OFF_VA;
    float* vB   = ws + OFF_VB;
    float* u    = ws + OFF_U;
    float* part = ws + OFF_PART;
    float* ctx  = ws + OFF_CTX;
    float* gb   = ws + OFF_GB;
    float* xg   = ws + OFF_XG;
    unsigned* bar = (unsigned*)(ws + OFF_BAR);
    unsigned short* bfb = (unsigned short*)(ws + FP32_WS_FLOATS);
    unsigned short* H3   = bfb + O_H3;
    unsigned short* WHI  = bfb + O_WHI;
    unsigned short* WLO  = bfb + O_WLO;
    unsigned short* A3X  = bfb + O_A3X;
    unsigned short* B3X  = bfb + O_B3X;
    unsigned short* B3L  = bfb + O_B3L;

    // u = W1e^T W2^T W3^T W4^T attn_w
    matvec_col_partial<<<32, 512, 0, stream>>>(fc4w, 512, 0, attnw, part);
    matvec_combine<<<1, 512, 0, stream>>>(part, vA);
    matvec_col_partial<<<32, 512, 0, stream>>>(fc3w, 512, 0, vA, part);
    matvec_combine<<<1, 512, 0, stream>>>(part, vB);
    matvec_col_partial<<<32, 512, 0, stream>>>(fc2w, 512, 0, vB, part);
    matvec_combine<<<1, 512, 0, stream>>>(part, vA);
    matvec_col_partial<<<32, 512, 0, stream>>>(fc1w, 1024, 0, vA, part);
    matvec_combine<<<1, 512, 0, stream>>>(part, u);

    attn_ctx<<<128, 256, 0, stream>>>(enc, u, ctx);

    // gbase = ctx @ Wc^T + b_ih + b_hh  (fp32 path, tiny)
    {
        dim3 g(16, 1);
        gemm_nt<<<g, 256, 0, stream>>>(128, 2048, 512, ctx, 512,
                                       wih, 1536, 1024, bih, bhh, gb);
    }

    // xgb = gather(emb, tgt) @ Wx^T + gb  via split-bf16 MFMA
    conv_split<<<2048, 256, 0, stream>>>(wih, 1536, 0, 1024, 0, 1, nullptr, B3X);
    conv_split<<<3456, 256, 0, stream>>>(emb, 1024, 0, 1024, 1, 0, tgt, A3X);
    {
        dim3 g(16, 27);
        gemm_bf16_nt<<<g, 256, 0, stream>>>(3456, 2048, 3072, A3X, 3072, 0, B3X,
                                            nullptr, gb, xg, 0);
    }

    // B3L overlays A3X/B3X — only after the xg gemm
    conv_split<<<8000, 256, 0, stream>>>(outw, 512, 0, 512, 0, 1, nullptr, B3L);
    // whh -> quad-interleaved hi/lo arrays
    conv_splitw<<<2048, 256, 0, stream>>>(whh, WHI, WLO);
    // h0 -> H3[0] compact [hi|lo]
    conv_splitc<<<128, 256, 0, stream>>>(ehs, H3);

    // persistent LSTM v4 (27 steps), XCD-local exchange + per-XCD flag barrier
    zero_bar<<<65, 256, 0, stream>>>(bar);
    lstm_persist4<<<256, 256, 0, stream>>>(H3, WHI, WLO, xg, bar);

    // logits = H3[1:] @ B3L^T + out_b (compact-A remap), scattered to (b, t, v)
    {
        dim3 g(63, 27);
        gemm_bf16_nt<<<g, 256, 0, stream>>>(3456, 8000, 1536,
                                            H3 + (size_t)128 * 1024, 1024, 1, B3L,
                                            outb, nullptr, out, 1);
    }

    argmax_k<<<864, 256, 0, stream>>>(out, out + (size_t)TT * 128 * VV);
}

// Round 14
// 571.587 us; speedup vs baseline: 1.5432x; 1.0904x over previous
//
#include <hip/hip_runtime.h>
#include <math.h>

#define BB 128
#define SS 80
#define HH 512
#define TT 27      // T-1
#define TFULL 28
#define VV 8000

typedef __attribute__((ext_vector_type(4))) float f32x4;
typedef __attribute__((ext_vector_type(8))) short bfrag;

// ---------------- fp32 workspace layout (floats) ----------------
#define OFF_VA   0
#define OFF_VB   512
#define OFF_U    1024
#define OFF_PART 1536
#define OFF_CTX  17920
#define OFF_GB   83456
#define OFF_XG   345600          // 3456*2048 (xg + gb folded)
#define OFF_BAR  7423488         // barrier region (flags + xcd counters)
#define FP32_WS_FLOATS 7489536
// ---------------- bf16 workspace (ushort offsets from bf16 base) ----------------
// ALL operands compact [hi|lo] now (hi duplication folded at address-gen).
#define O_H3     0               // 28*128 rows x 1024 [hi|lo]
#define O_WHI    3670016         // 2048 quad rows x 512 (hi)
#define O_WLO    4718592         // 2048 quad rows x 512 (lo)
#define O_R      5767168
#define O_A3X    O_R             // 3456 x 2048 [hi|lo]
#define O_B3X    (O_R + 7077888) // 2048 x 2048 [hi|lo]
#define O_B3L    O_R             // 8000 x 1024 [hi|lo] (overlays after xg gemm)

__device__ __forceinline__ unsigned short f2bf(float x) {
    unsigned int u = __float_as_uint(x);
    unsigned int r = (u + 0x7fff + ((u >> 16) & 1)) >> 16;
    return (unsigned short)r;
}
__device__ __forceinline__ float bf2f(unsigned short h) {
    return __uint_as_float(((unsigned int)h) << 16);
}
__device__ __forceinline__ void gload16(void* lds, const void* g) {
    __builtin_amdgcn_global_load_lds(
        (__attribute__((address_space(1))) void*)g,
        (__attribute__((address_space(3))) void*)lds, 16, 0, 0);
}
// sc0 (L1-bypass, L2-served): fresh within-XCD reads, no invalidate
__device__ __forceinline__ void gload16s(void* lds, const void* g) {
    __builtin_amdgcn_global_load_lds(
        (__attribute__((address_space(1))) void*)g,
        (__attribute__((address_space(3))) void*)lds, 16, 0, 1);
}

__global__ __launch_bounds__(256) void zero_bar(unsigned* b) {
    int i = blockIdx.x * 256 + threadIdx.x;
    if (i < 16512) b[i] = 0u;
}

// ---------- compact [hi|lo] split conversion: K floats -> 2K ushorts ----------
// mode 0: src row = r ; mode 1: gather emb row = gidx[(r&127)*28 + (r>>7)]
__global__ __launch_bounds__(256) void conv_cpk(
    const float* __restrict__ src, int ld, int K,
    int mode, const int* __restrict__ gidx,
    unsigned short* __restrict__ dst)
{
    int r = blockIdx.x;
    int sr = r;
    if (mode == 1) { int b = r & 127, t = r >> 7; sr = gidx[b * TFULL + t]; }
    const float* s = src + (size_t)sr * ld;
    unsigned short* d = dst + (size_t)r * (2 * K);
    for (int c = threadIdx.x * 4; c < K; c += 1024) {
        float4 v = *(const float4*)(s + c);
        ushort4 hi, lo;
        hi.x = f2bf(v.x); lo.x = f2bf(v.x - bf2f(hi.x));
        hi.y = f2bf(v.y); lo.y = f2bf(v.y - bf2f(hi.y));
        hi.z = f2bf(v.z); lo.z = f2bf(v.z - bf2f(hi.z));
        hi.w = f2bf(v.w); lo.w = f2bf(v.w - bf2f(hi.w));
        *(ushort4*)(d + c) = hi;
        *(ushort4*)(d + K + c) = lo;
    }
}

// whh -> quad-interleaved rows (r -> gate r&3, k r>>2), separate hi / lo arrays
__global__ __launch_bounds__(256) void conv_splitw(
    const float* __restrict__ src,
    unsigned short* __restrict__ whi, unsigned short* __restrict__ wlo)
{
    int r = blockIdx.x;
    int sr = (r & 3) * 512 + (r >> 2);
    const float* s = src + (size_t)sr * 512;
    int c = threadIdx.x * 2;
    float2 v = *(const float2*)(s + c);
    unsigned short hx = f2bf(v.x), hy = f2bf(v.y);
    whi[(size_t)r * 512 + c] = hx;
    whi[(size_t)r * 512 + c + 1] = hy;
    wlo[(size_t)r * 512 + c] = f2bf(v.x - bf2f(hx));
    wlo[(size_t)r * 512 + c + 1] = f2bf(v.y - bf2f(hy));
}

// ---------- bf16 MFMA GEMM: dbuf + counted vmcnt, COMPACT operands ----------
// Logical K3 = 3*K. A compact [hi|lo] (2K wide): ek0a = k0>=aK ? k0-aK : k0
// (A-side [hi|hi|lo]). B compact: ek0b = k0>=2*bK ? k0-2*bK : k0 ([hi|lo|hi]).
// outMode 0: C[m*N+n]   outMode 1: C[((m&127)*27 + (m>>7))*8000 + n]
__global__ __launch_bounds__(256) void gemm_bf16_nt(
    int M, int N, int K3,
    const unsigned short* __restrict__ A3, int astride, int aK,
    const unsigned short* __restrict__ B3, int bstride, int bK,
    const float* __restrict__ bias,
    const float* __restrict__ addmat,
    float* __restrict__ C, int outMode)
{
    __shared__ unsigned short Asm[2][128 * 64];
    __shared__ unsigned short Bsm[2][128 * 64];
    int tid = threadIdx.x, wave = tid >> 6, lane = tid & 63;

    // ---- block swizzle: XCD-contiguous lid, then GROUP=9 m-fast supertiles ----
    int nT = gridDim.x, mT = gridDim.y;
    int p = blockIdx.y * nT + blockIdx.x;
    int nwg = nT * mT;
    int q = nwg >> 3, rr = nwg & 7;
    int xcd = p & 7, pos = p >> 3;
    int lid = (xcd < rr) ? (xcd * (q + 1) + pos) : (rr * (q + 1) + (xcd - rr) * q + pos);
    const int GROUP = 9;
    int width = GROUP * nT;
    int gid2 = lid / width;
    int first_m = gid2 * GROUP;
    int gsz = mT - first_m; if (gsz > GROUP) gsz = GROUP;
    int rem = lid - gid2 * width;
    int mt = first_m + rem % gsz;
    int nt = rem / gsz;
    int m0 = mt * 128, n0 = nt * 128;

    int wm0 = (wave >> 1) * 64, wn0 = (wave & 1) * 64;
    f32x4 acc[4][4];
    #pragma unroll
    for (int i = 0; i < 4; ++i)
        #pragma unroll
        for (int j = 0; j < 4; ++j) acc[i][j] = (f32x4){0.f, 0.f, 0.f, 0.f};

    int srow8 = lane >> 3;             // row within 8-row chunk
    int schunk = lane & 7;             // 16B chunk within 128B row

    auto STAGE = [&](int buf, int k0) {
        int ek0a = (k0 >= aK) ? k0 - aK : k0;
        int ek0b = (k0 >= 2 * bK) ? k0 - 2 * bK : k0;
        #pragma unroll
        for (int rep = 0; rep < 4; ++rep) {
            int ci = wave * 4 + rep;
            int row = ci * 8 + srow8;
            int sc = schunk ^ (row & 7);
            int gm = m0 + row; if (gm >= M) gm = M - 1;
            gload16(Asm[buf] + ci * 512 + lane * 8,
                    A3 + (size_t)gm * astride + ek0a + sc * 8);
            int gn = n0 + row; if (gn >= N) gn = N - 1;
            gload16(Bsm[buf] + ci * 512 + lane * 8,
                    B3 + (size_t)gn * bstride + ek0b + sc * 8);
        }
    };

    int nK = K3 >> 6;
    STAGE(0, 0);
    STAGE(1, 64);
    for (int kc = 0; kc < nK; ++kc) {
        if (kc < nK - 1) asm volatile("s_waitcnt vmcnt(8)" ::: "memory");
        else             asm volatile("s_waitcnt vmcnt(0)" ::: "memory");
        __builtin_amdgcn_s_barrier();
        const unsigned short* Ab = Asm[kc & 1];
        const unsigned short* Bb = Bsm[kc & 1];
        #pragma unroll
        for (int ks = 0; ks < 2; ++ks) {
            bfrag a[4], b[4];
            #pragma unroll
            for (int i = 0; i < 4; ++i) {
                int ar = wm0 + i * 16 + (lane & 15);
                int ab = (ar * 128 + ks * 64 + (lane >> 4) * 16) ^ ((ar & 7) << 4);
                a[i] = *(const bfrag*)((const char*)Ab + ab);
                int br = wn0 + i * 16 + (lane & 15);
                int bb = (br * 128 + ks * 64 + (lane >> 4) * 16) ^ ((br & 7) << 4);
                b[i] = *(const bfrag*)((const char*)Bb + bb);
            }
            #pragma unroll
            for (int i = 0; i < 4; ++i)
                #pragma unroll
                for (int j = 0; j < 4; ++j)
                    acc[i][j] = __builtin_amdgcn_mfma_f32_16x16x32_bf16(a[i], b[j], acc[i][j], 0, 0, 0);
        }
        __builtin_amdgcn_s_barrier();
        if (kc + 2 < nK) STAGE(kc & 1, (kc + 2) * 64);
    }
    #pragma unroll
    for (int i = 0; i < 4; ++i) {
        #pragma unroll
        for (int r = 0; r < 4; ++r) {
            int m = m0 + wm0 + i * 16 + ((lane >> 4) << 2) + r;
            if (m >= M) continue;
            #pragma unroll
            for (int j = 0; j < 4; ++j) {
                int n = n0 + wn0 + j * 16 + (lane & 15);
                if (n >= N) continue;
                float v = acc[i][j][r];
                if (bias) v += bias[n];
                if (addmat) v += addmat[(size_t)(m & 127) * 2048 + n];
                size_t oi;
                if (outMode == 0) oi = (size_t)m * N + n;
                else { int bb2 = m & 127, tt = m >> 7; oi = ((size_t)bb2 * TT + tt) * (size_t)VV + n; }
                __builtin_nontemporal_store(v, &C[oi]);
            }
        }
    }
}

// ---------- persistent LSTM v4: XCD-local (R12-proven) + reg-resident W-lo ----------
__global__ __launch_bounds__(256, 1) void lstm_persist4(
    unsigned short* __restrict__ H3,        // 28*128 x 1024 [hi|lo]
    const unsigned short* __restrict__ Whi, // 2048 quad rows x 512 (hi)
    const unsigned short* __restrict__ Wlo, // 2048 quad rows x 512 (lo)
    const float* __restrict__ xgb,          // 3456 x 2048 (xg + gb)
    unsigned* bar)                          // flags: xcd*2048+slot*16 ; ctr: 16384+xcd*16
{
    __shared__ unsigned short Wl[64 * 512];   // 65536 B (W-hi slice)
    __shared__ unsigned short Al[16 * 1024];  // 32768 B (A compact)
    __shared__ int s_ids[2];

    int tid = threadIdx.x, wv = tid >> 6, lane = tid & 63;
    if (tid == 0) {
        unsigned x;
        asm volatile("s_getreg_b32 %0, hwreg(HW_REG_XCC_ID)" : "=s"(x));
        x &= 7u;
        unsigned s = __hip_atomic_fetch_add(bar + 16384 + x * 16, 1u,
                        __ATOMIC_RELAXED, __HIP_MEMORY_SCOPE_AGENT);
        s_ids[0] = (int)x;
        s_ids[1] = (int)(s & 31u);
    }
    __syncthreads();
    int xcd = s_ids[0], slot = s_ids[1];
    int b0 = xcd * 16;              // batch rows [b0, b0+16)
    int nq0 = slot * 64;            // quad rows [nq0, nq0+64)

    int l15 = lane & 15, g4 = (lane >> 4) << 4;
    int arow = l15;                 // A row (m)
    int wr = wv * 16 + l15;         // W-hi LDS row (0..63)
    int n_local = wv * 16 + l15;
    int g = n_local & 3;            // gate
    int kglob = slot * 16 + (n_local >> 2);
    const unsigned short* wloRow = Wlo + (size_t)(nq0 + n_local) * 512;
    float creg[4] = {0.f, 0.f, 0.f, 0.f};

    // stage W-hi slice once: 64 rows x 512 elems (64 x 16B chunks per row)
    {
        const unsigned short* Wsrc = Whi + (size_t)nq0 * 512;
        #pragma unroll
        for (int j = 0; j < 16; ++j) {
            int ci = j * 256 + tid;
            int row = ci >> 6, cc = ci & 63;
            int sc = cc ^ (row & 7);
            gload16(Wl + ci * 8, Wsrc + (size_t)row * 512 + sc * 8);
        }
        asm volatile("s_waitcnt vmcnt(0)" ::: "memory");
    }
    // W-lo fragments are STEP-INVARIANT: preload once into registers
    bfrag wlo[16];
    #pragma unroll
    for (int c = 0; c < 16; ++c)
        wlo[c] = *(const bfrag*)(wloRow + c * 32 + (lane >> 4) * 8);
    __syncthreads();

    for (int t = 0; t < TT; ++t) {
        // stage A: 16 rows x 1024 elems via sc0 (fresh from own-XCD L2)
        const unsigned short* Asrc = H3 + ((size_t)t * 128 + b0) * 1024;
        #pragma unroll
        for (int j = 0; j < 8; ++j) {
            int ci = j * 256 + tid;
            int row = ci >> 7, cc = ci & 127;
            int sc = cc ^ (row & 7);
            gload16s(Al + ci * 8, Asrc + (size_t)row * 1024 + sc * 8);
        }
        // prefetch epilogue xgb values; counted vmcnt leaves them in flight
        float xpre[4];
        #pragma unroll
        for (int r = 0; r < 4; ++r) {
            int m_local = ((lane >> 4) << 2) + r;
            xpre[r] = xgb[(((size_t)t * 128 + b0 + m_local) << 11) + (size_t)g * 512 + kglob];
        }
        asm volatile("s_waitcnt vmcnt(4)" ::: "memory");   // A-stage (8) done; 4 xpre in flight
        __builtin_amdgcn_s_barrier();

        f32x4 acc0 = (f32x4){0.f, 0.f, 0.f, 0.f};
        f32x4 acc1 = acc0, acc2 = acc0, acc3 = acc0;
        // region 0: a=hi(c), w=hi(c)  [4 independent chains]
        #pragma unroll
        for (int c = 0; c < 16; ++c) {
            int ab = (arow * 2048 + c * 64 + g4) ^ ((arow & 7) << 4);
            int wb = (wr * 1024 + c * 64 + g4) ^ ((wr & 7) << 4);
            bfrag a = *(const bfrag*)((const char*)Al + ab);
            bfrag w = *(const bfrag*)((const char*)Wl + wb);
            switch (c & 3) {
                case 0: acc0 = __builtin_amdgcn_mfma_f32_16x16x32_bf16(a, w, acc0, 0, 0, 0); break;
                case 1: acc1 = __builtin_amdgcn_mfma_f32_16x16x32_bf16(a, w, acc1, 0, 0, 0); break;
                case 2: acc2 = __builtin_amdgcn_mfma_f32_16x16x32_bf16(a, w, acc2, 0, 0, 0); break;
                default: acc3 = __builtin_amdgcn_mfma_f32_16x16x32_bf16(a, w, acc3, 0, 0, 0); break;
            }
        }
        // region 1: a=hi(c), w=lo(c) from REGISTERS (pure-reg MFMA)
        #pragma unroll
        for (int c = 0; c < 16; ++c) {
            int ab = (arow * 2048 + c * 64 + g4) ^ ((arow & 7) << 4);
            bfrag a = *(const bfrag*)((const char*)Al + ab);
            switch (c & 3) {
                case 0: acc0 = __builtin_amdgcn_mfma_f32_16x16x32_bf16(a, wlo[c], acc0, 0, 0, 0); break;
                case 1: acc1 = __builtin_amdgcn_mfma_f32_16x16x32_bf16(a, wlo[c], acc1, 0, 0, 0); break;
                case 2: acc2 = __builtin_amdgcn_mfma_f32_16x16x32_bf16(a, wlo[c], acc2, 0, 0, 0); break;
                default: acc3 = __builtin_amdgcn_mfma_f32_16x16x32_bf16(a, wlo[c], acc3, 0, 0, 0); break;
            }
        }
        // region 2: a=lo(16+c), w=hi(c)
        #pragma unroll
        for (int c = 0; c < 16; ++c) {
            int ab = (arow * 2048 + (16 + c) * 64 + g4) ^ ((arow & 7) << 4);
            int wb = (wr * 1024 + c * 64 + g4) ^ ((wr & 7) << 4);
            bfrag a = *(const bfrag*)((const char*)Al + ab);
            bfrag w = *(const bfrag*)((const char*)Wl + wb);
            switch (c & 3) {
                case 0: acc0 = __builtin_amdgcn_mfma_f32_16x16x32_bf16(a, w, acc0, 0, 0, 0); break;
                case 1: acc1 = __builtin_amdgcn_mfma_f32_16x16x32_bf16(a, w, acc1, 0, 0, 0); break;
                case 2: acc2 = __builtin_amdgcn_mfma_f32_16x16x32_bf16(a, w, acc2, 0, 0, 0); break;
                default: acc3 = __builtin_amdgcn_mfma_f32_16x16x32_bf16(a, w, acc3, 0, 0, 0); break;
            }
        }
        f32x4 accT = (acc0 + acc1) + (acc2 + acc3);

        // epilogue: xpre add, shfl-down gate gather, LSTM update, compact h write
        #pragma unroll
        for (int r = 0; r < 4; ++r) {
            int m_local = ((lane >> 4) << 2) + r;
            int b = b0 + m_local;
            float v = accT[r] + xpre[r];
            float f1 = __shfl_down(v, 1);
            float f2 = __shfl_down(v, 2);
            float f3 = __shfl_down(v, 3);
            if ((lane & 3) == 0) {
                float si = 1.f / (1.f + expf(-v));
                float sf = 1.f / (1.f + expf(-f1));
                float tg = tanhf(f2);
                float so = 1.f / (1.f + expf(-f3));
                float cn = sf * creg[r] + si * tg;
                float hn = so * tanhf(cn);
                creg[r] = cn;
                unsigned short hi = f2bf(hn);
                unsigned short lo = f2bf(hn - bf2f(hi));
                unsigned short* hr = H3 + ((size_t)(t + 1) * 128 + b) * 1024;
                hr[kglob] = hi; hr[512 + kglob] = lo;
            }
        }

        if (t != TT - 1) {
            // XCD-local barrier: stores committed to L2, then flag; 32 threads
            // poll the 32 per-slot flags in parallel. No fences, L2 stays warm.
            asm volatile("s_waitcnt vmcnt(0)" ::: "memory");
            __syncthreads();
            unsigned ph = (unsigned)(t + 1);
            if (tid == 0)
                __hip_atomic_store(bar + xcd * 2048 + slot * 16, ph,
                                   __ATOMIC_RELAXED, __HIP_MEMORY_SCOPE_AGENT);
            if (tid < 32) {
                unsigned* fl = bar + xcd * 2048 + tid * 16;
                while (__hip_atomic_load(fl, __ATOMIC_RELAXED,
                                         __HIP_MEMORY_SCOPE_AGENT) < ph)
                    __builtin_amdgcn_s_sleep(1);
            }
            __syncthreads();
        }
    }
}

// ---------- small helpers ----------
__global__ __launch_bounds__(512) void matvec_col_partial(
    const float* __restrict__ W, int ldw, int koff,
    const float* __restrict__ vin, float* __restrict__ part)
{
    int k = threadIdx.x;
    int o0 = blockIdx.x * 16;
    float acc = 0.f;
    #pragma unroll
    for (int o = 0; o < 16; ++o)
        acc += W[(size_t)(o0 + o) * ldw + koff + k] * vin[o0 + o];
    part[blockIdx.x * 512 + k] = acc;
}

__global__ __launch_bounds__(512) void matvec_combine(
    const float* __restrict__ part, float* __restrict__ vout)
{
    int k = threadIdx.x;
    float s = 0.f;
    #pragma unroll
    for (int c = 0; c < 32; ++c) s += part[c * 512 + k];
    vout[k] = s;
}

__global__ __launch_bounds__(256) void attn_ctx(
    const float* __restrict__ enc, const float* __restrict__ u,
    float* __restrict__ ctx)
{
    __shared__ float su[HH];
    __shared__ float sw[SS];
    __shared__ float ssum;
    int b = blockIdx.x, tid = threadIdx.x;
    su[tid] = u[tid];
    su[tid + 256] = u[tid + 256];
    __syncthreads();
    const float* eb = enc + (size_t)b * SS * HH;
    int wave = tid >> 6, lane = tid & 63;
    for (int s = wave; s < SS; s += 4) {
        const float* row = eb + s * HH;
        float acc = 0.f;
        for (int k = lane; k < HH; k += 64) acc += row[k] * su[k];
        #pragma unroll
        for (int off = 32; off; off >>= 1) acc += __shfl_down(acc, off);
        if (lane == 0) sw[s] = acc;
    }
    __syncthreads();
    if (tid == 0) {
        float mx = sw[0];
        for (int s = 1; s < SS; ++s) mx = fmaxf(mx, sw[s]);
        float sum = 0.f;
        for (int s = 0; s < SS; ++s) { float e = expf(sw[s] - mx); sw[s] = e; sum += e; }
        ssum = sum;
    }
    __syncthreads();
    float inv = 1.0f / ssum;
    for (int k = tid; k < HH; k += 256) {
        float acc = 0.f;
        #pragma unroll 4
        for (int s = 0; s < SS; ++s) acc += sw[s] * eb[s * HH + k];
        ctx[(size_t)b * HH + k] = acc * inv;
    }
}

// fp32 vector GEMM, kept only for gbase (ctx @ Wc^T + b_ih + b_hh)
__global__ __launch_bounds__(256) void gemm_nt(
    int M, int N, int K,
    const float* __restrict__ A, int lda,
    const float* __restrict__ Bm, int ldb, int kob,
    const float* __restrict__ bias1, const float* __restrict__ bias2,
    float* __restrict__ C)
{
    __shared__ float As[16][132];
    __shared__ float Bs[16][132];
    int tid = threadIdx.x;
    int m0 = blockIdx.y * 128, n0 = blockIdx.x * 128;
    int tn = tid & 15, tm = tid >> 4;
    float acc[8][8];
    #pragma unroll
    for (int i = 0; i < 8; ++i)
        #pragma unroll
        for (int j = 0; j < 8; ++j) acc[i][j] = 0.f;
    int lr = tid >> 2;
    int lk = (tid & 3) * 4;
    for (int k0 = 0; k0 < K; k0 += 16) {
        #pragma unroll
        for (int half = 0; half < 2; ++half) {
            int mr = lr + half * 64;
            int m = m0 + mr;
            float4 va = make_float4(0.f, 0.f, 0.f, 0.f);
            if (m < M) va = *(const float4*)(A + (size_t)m * lda + k0 + lk);
            As[lk + 0][mr] = va.x; As[lk + 1][mr] = va.y;
            As[lk + 2][mr] = va.z; As[lk + 3][mr] = va.w;
            int n = n0 + mr;
            float4 vb = make_float4(0.f, 0.f, 0.f, 0.f);
            if (n < N) vb = *(const float4*)(Bm + (size_t)n * ldb + kob + k0 + lk);
            Bs[lk + 0][mr] = vb.x; Bs[lk + 1][mr] = vb.y;
            Bs[lk + 2][mr] = vb.z; Bs[lk + 3][mr] = vb.w;
        }
        __syncthreads();
        #pragma unroll
        for (int kk = 0; kk < 16; ++kk) {
            float4 a0 = *(const float4*)&As[kk][tm * 8];
            float4 a1 = *(const float4*)&As[kk][tm * 8 + 4];
            float4 b0 = *(const float4*)&Bs[kk][tn * 8];
            float4 b1 = *(const float4*)&Bs[kk][tn * 8 + 4];
            float av[8] = {a0.x, a0.y, a0.z, a0.w, a1.x, a1.y, a1.z, a1.w};
            float bv[8] = {b0.x, b0.y, b0.z, b0.w, b1.x, b1.y, b1.z, b1.w};
            #pragma unroll
            for (int i = 0; i < 8; ++i)
                #pragma unroll
                for (int j = 0; j < 8; ++j)
                    acc[i][j] += av[i] * bv[j];
        }
        __syncthreads();
    }
    #pragma unroll
    for (int i = 0; i < 8; ++i) {
        int m = m0 + tm * 8 + i;
        if (m >= M) continue;
        #pragma unroll
        for (int j = 0; j < 8; ++j) {
            int n = n0 + tn * 8 + j;
            if (n >= N) continue;
            float v = acc[i][j];
            if (bias1) v += bias1[n];
            if (bias2) v += bias2[n];
            C[(size_t)m * N + n] = v;
        }
    }
}

__global__ __launch_bounds__(256) void argmax_k(
    const float* __restrict__ logits, float* __restrict__ preds)
{
    int r = blockIdx.x * 4 + (threadIdx.x >> 6);
    int lane = threadIdx.x & 63;
    const float* row = logits + (size_t)r * VV;
    float best = -INFINITY;
    int bi = 0;
    for (int v = lane; v < VV; v += 64) {
        float x = row[v];
        if (x > best) { best = x; bi = v; }
    }
    #pragma unroll
    for (int off = 32; off; off >>= 1) {
        float ob = __shfl_down(best, off);
        int oi = __shfl_down(bi, off);
        if (ob > best || (ob == best && oi < bi)) { best = ob; bi = oi; }
    }
    if (lane == 0) preds[r] = (float)bi;
}

extern "C" void kernel_launch(void* const* d_in, const int* in_sizes, int n_in,
                              void* d_out, int out_size, void* d_ws, size_t ws_size,
                              hipStream_t stream) {
    const float* ehs   = (const float*)d_in[0];
    const float* enc   = (const float*)d_in[1];
    const int*   tgt   = (const int*)d_in[2];
    const float* emb   = (const float*)d_in[4];
    const float* fc1w  = (const float*)d_in[5];
    const float* fc2w  = (const float*)d_in[7];
    const float* fc3w  = (const float*)d_in[9];
    const float* fc4w  = (const float*)d_in[11];
    const float* attnw = (const float*)d_in[13];
    const float* wih   = (const float*)d_in[14];
    const float* whh   = (const float*)d_in[15];
    const float* bih   = (const float*)d_in[16];
    const float* bhh   = (const float*)d_in[17];
    const float* outw  = (const float*)d_in[18];
    const float* outb  = (const float*)d_in[19];
    float* out = (float*)d_out;
    float* ws  = (float*)d_ws;

    float* vA   = ws + OFF_VA;
    float* vB   = ws + OFF_VB;
    float* u    = ws + OFF_U;
    float* part = ws + OFF_PART;
    float* ctx  = ws + OFF_CTX;
    float* gb   = ws + OFF_GB;
    float* xg   = ws + OFF_XG;
    unsigned* bar = (unsigned*)(ws + OFF_BAR);
    unsigned short* bfb = (unsigned short*)(ws + FP32_WS_FLOATS);
    unsigned short* H3   = bfb + O_H3;
    unsigned short* WHI  = bfb + O_WHI;
    unsigned short* WLO  = bfb + O_WLO;
    unsigned short* A3X  = bfb + O_A3X;
    unsigned short* B3X  = bfb + O_B3X;
    unsigned short* B3L  = bfb + O_B3L;

    // u = W1e^T W2^T W3^T W4^T attn_w
    matvec_col_partial<<<32, 512, 0, stream>>>(fc4w, 512, 0, attnw, part);
    matvec_combine<<<1, 512, 0, stream>>>(part, vA);
    matvec_col_partial<<<32, 512, 0, stream>>>(fc3w, 512, 0, vA, part);
    matvec_combine<<<1, 512, 0, stream>>>(part, vB);
    matvec_col_partial<<<32, 512, 0, stream>>>(fc2w, 512, 0, vB, part);
    matvec_combine<<<1, 512, 0, stream>>>(part, vA);
    matvec_col_partial<<<32, 512, 0, stream>>>(fc1w, 1024, 0, vA, part);
    matvec_combine<<<1, 512, 0, stream>>>(part, u);

    attn_ctx<<<128, 256, 0, stream>>>(enc, u, ctx);

    // gbase = ctx @ Wc^T + b_ih + b_hh  (fp32 path, tiny)
    {
        dim3 g(16, 1);
        gemm_nt<<<g, 256, 0, stream>>>(128, 2048, 512, ctx, 512,
                                       wih, 1536, 1024, bih, bhh, gb);
    }

    // xgb = gather(emb, tgt) @ Wx^T + gb  via split-bf16 MFMA (compact operands)
    conv_cpk<<<2048, 256, 0, stream>>>(wih, 1536, 1024, 0, nullptr, B3X);
    conv_cpk<<<3456, 256, 0, stream>>>(emb, 1024, 1024, 1, tgt, A3X);
    {
        dim3 g(16, 27);
        gemm_bf16_nt<<<g, 256, 0, stream>>>(3456, 2048, 3072,
                                            A3X, 2048, 1024,
                                            B3X, 2048, 1024,
                                            nullptr, gb, xg, 0);
    }

    // B3L overlays A3X/B3X — only after the xg gemm
    conv_cpk<<<8000, 256, 0, stream>>>(outw, 512, 512, 0, nullptr, B3L);
    // whh -> quad-interleaved hi/lo arrays
    conv_splitw<<<2048, 256, 0, stream>>>(whh, WHI, WLO);
    // h0 -> H3[0] compact [hi|lo]
    conv_cpk<<<128, 256, 0, stream>>>(ehs, 512, 512, 0, nullptr, H3);

    // persistent LSTM v4 (27 steps), XCD-local exchange + per-XCD flag barrier
    zero_bar<<<65, 256, 0, stream>>>(bar);
    lstm_persist4<<<256, 256, 0, stream>>>(H3, WHI, WLO, xg, bar);

    // logits = H3[1:] @ B3L^T + out_b (compact A and B), scattered to (b, t, v)
    {
        dim3 g(63, 27);
        gemm_bf16_nt<<<g, 256, 0, stream>>>(3456, 8000, 1536,
                                            H3 + (size_t)128 * 1024, 1024, 512,
                                            B3L, 1024, 512,
                                            outb, nullptr, out, 1);
    }

    argmax_k<<<864, 256, 0, stream>>>(out, out + (size_t)TT * 128 * VV);
}

// Round 15
// 559.266 us; speedup vs baseline: 1.5772x; 1.0220x over previous
//
#include <hip/hip_runtime.h>
#include <math.h>

#define BB 128
#define SS 80
#define HH 512
#define TT 27      // T-1
#define TFULL 28
#define VV 8000

typedef __attribute__((ext_vector_type(4))) float f32x4;
typedef __attribute__((ext_vector_type(8))) short bfrag;

// ---------------- fp32 workspace layout (floats) ----------------
#define OFF_VA   0
#define OFF_VB   512
#define OFF_U    1024
#define OFF_PART 1536
#define OFF_CTX  17920
#define OFF_GB   83456
#define OFF_XG   345600          // 3456*2048 (xg + gb folded)
#define OFF_BAR  7423488         // barrier region (flags + xcd counters) + pmax
#define FP32_WS_FLOATS 7489536
// ---------------- bf16 workspace (ushort offsets from bf16 base) ----------------
#define O_H3     0               // 28*128 rows x 1024 [hi|lo]
#define O_WHI    3670016         // 2048 quad rows x 512 (hi)
#define O_WLO    4718592         // 2048 quad rows x 512 (lo)
#define O_R      5767168
#define O_A3X    O_R             // 3456 x 2048 [hi|lo]
#define O_B3X    (O_R + 7077888) // 2048 x 2048 [hi|lo]
#define O_B3L    O_R             // 8000 x 1024 [hi|lo] (overlays after xg gemm)

__device__ __forceinline__ unsigned short f2bf(float x) {
    unsigned int u = __float_as_uint(x);
    unsigned int r = (u + 0x7fff + ((u >> 16) & 1)) >> 16;
    return (unsigned short)r;
}
__device__ __forceinline__ float bf2f(unsigned short h) {
    return __uint_as_float(((unsigned int)h) << 16);
}
__device__ __forceinline__ void gload16(void* lds, const void* g) {
    __builtin_amdgcn_global_load_lds(
        (__attribute__((address_space(1))) void*)g,
        (__attribute__((address_space(3))) void*)lds, 16, 0, 0);
}
// sc0 (L1-bypass, L2-served): fresh within-XCD reads, no invalidate
__device__ __forceinline__ void gload16s(void* lds, const void* g) {
    __builtin_amdgcn_global_load_lds(
        (__attribute__((address_space(1))) void*)g,
        (__attribute__((address_space(3))) void*)lds, 16, 0, 1);
}

// zero bar flags (16512 u32) + pmax (3456 u64 = 6912 u32), contiguous
__global__ __launch_bounds__(256) void zero_bar(unsigned* b) {
    int i = blockIdx.x * 256 + threadIdx.x;
    if (i < 23424) b[i] = 0u;
}

__global__ __launch_bounds__(256) void unpack_preds(
    const unsigned long long* __restrict__ pmax, float* __restrict__ preds)
{
    int r = blockIdx.x * 256 + threadIdx.x;
    if (r < TT * 128) preds[r] = (float)(8191 - (int)(pmax[r] & 8191ull));
}

// ---------- compact [hi|lo] split conversion: K floats -> 2K ushorts ----------
// mode 0: src row = r ; mode 1: gather emb row = gidx[(r&127)*28 + (r>>7)]
__global__ __launch_bounds__(256) void conv_cpk(
    const float* __restrict__ src, int ld, int K,
    int mode, const int* __restrict__ gidx,
    unsigned short* __restrict__ dst)
{
    int r = blockIdx.x;
    int sr = r;
    if (mode == 1) { int b = r & 127, t = r >> 7; sr = gidx[b * TFULL + t]; }
    const float* s = src + (size_t)sr * ld;
    unsigned short* d = dst + (size_t)r * (2 * K);
    for (int c = threadIdx.x * 4; c < K; c += 1024) {
        float4 v = *(const float4*)(s + c);
        ushort4 hi, lo;
        hi.x = f2bf(v.x); lo.x = f2bf(v.x - bf2f(hi.x));
        hi.y = f2bf(v.y); lo.y = f2bf(v.y - bf2f(hi.y));
        hi.z = f2bf(v.z); lo.z = f2bf(v.z - bf2f(hi.z));
        hi.w = f2bf(v.w); lo.w = f2bf(v.w - bf2f(hi.w));
        *(ushort4*)(d + c) = hi;
        *(ushort4*)(d + K + c) = lo;
    }
}

// whh -> quad-interleaved rows (r -> gate r&3, k r>>2), separate hi / lo arrays
__global__ __launch_bounds__(256) void conv_splitw(
    const float* __restrict__ src,
    unsigned short* __restrict__ whi, unsigned short* __restrict__ wlo)
{
    int r = blockIdx.x;
    int sr = (r & 3) * 512 + (r >> 2);
    const float* s = src + (size_t)sr * 512;
    int c = threadIdx.x * 2;
    float2 v = *(const float2*)(s + c);
    unsigned short hx = f2bf(v.x), hy = f2bf(v.y);
    whi[(size_t)r * 512 + c] = hx;
    whi[(size_t)r * 512 + c + 1] = hy;
    wlo[(size_t)r * 512 + c] = f2bf(v.x - bf2f(hx));
    wlo[(size_t)r * 512 + c + 1] = f2bf(v.y - bf2f(hy));
}

// ---------- bf16 MFMA GEMM: dbuf + counted vmcnt, COMPACT operands ----------
// Logical K3 = 3*K. A compact [hi|lo] (2K wide): ek0a = k0>=aK ? k0-aK : k0
// (A-side [hi|hi|lo]). B compact: ek0b = k0>=2*bK ? k0-2*bK : k0 ([hi|lo|hi]).
// outMode 0: C[m*N+n]   outMode 1: C[((m&127)*27 + (m>>7))*8000 + n]
// pmax (outMode 1): fused deterministic row-argmax via packed u64 atomicMax.
__global__ __launch_bounds__(256) void gemm_bf16_nt(
    int M, int N, int K3,
    const unsigned short* __restrict__ A3, int astride, int aK,
    const unsigned short* __restrict__ B3, int bstride, int bK,
    const float* __restrict__ bias,
    const float* __restrict__ addmat,
    float* __restrict__ C, int outMode,
    unsigned long long* __restrict__ pmax)
{
    __shared__ unsigned short Asm[2][128 * 64];
    __shared__ unsigned short Bsm[2][128 * 64];
    int tid = threadIdx.x, wave = tid >> 6, lane = tid & 63;

    // ---- block swizzle: XCD-contiguous lid, then GROUP=9 m-fast supertiles ----
    int nT = gridDim.x, mT = gridDim.y;
    int p = blockIdx.y * nT + blockIdx.x;
    int nwg = nT * mT;
    int q = nwg >> 3, rr = nwg & 7;
    int xcd = p & 7, pos = p >> 3;
    int lid = (xcd < rr) ? (xcd * (q + 1) + pos) : (rr * (q + 1) + (xcd - rr) * q + pos);
    const int GROUP = 9;
    int width = GROUP * nT;
    int gid2 = lid / width;
    int first_m = gid2 * GROUP;
    int gsz = mT - first_m; if (gsz > GROUP) gsz = GROUP;
    int rem = lid - gid2 * width;
    int mt = first_m + rem % gsz;
    int nt = rem / gsz;
    int m0 = mt * 128, n0 = nt * 128;

    int wm0 = (wave >> 1) * 64, wn0 = (wave & 1) * 64;
    f32x4 acc[4][4];
    #pragma unroll
    for (int i = 0; i < 4; ++i)
        #pragma unroll
        for (int j = 0; j < 4; ++j) acc[i][j] = (f32x4){0.f, 0.f, 0.f, 0.f};

    int srow8 = lane >> 3;             // row within 8-row chunk
    int schunk = lane & 7;             // 16B chunk within 128B row

    auto STAGE = [&](int buf, int k0) {
        int ek0a = (k0 >= aK) ? k0 - aK : k0;
        int ek0b = (k0 >= 2 * bK) ? k0 - 2 * bK : k0;
        #pragma unroll
        for (int rep = 0; rep < 4; ++rep) {
            int ci = wave * 4 + rep;
            int row = ci * 8 + srow8;
            int sc = schunk ^ (row & 7);
            int gm = m0 + row; if (gm >= M) gm = M - 1;
            gload16(Asm[buf] + ci * 512 + lane * 8,
                    A3 + (size_t)gm * astride + ek0a + sc * 8);
            int gn = n0 + row; if (gn >= N) gn = N - 1;
            gload16(Bsm[buf] + ci * 512 + lane * 8,
                    B3 + (size_t)gn * bstride + ek0b + sc * 8);
        }
    };

    int nK = K3 >> 6;
    STAGE(0, 0);
    STAGE(1, 64);
    for (int kc = 0; kc < nK; ++kc) {
        if (kc < nK - 1) asm volatile("s_waitcnt vmcnt(8)" ::: "memory");
        else             asm volatile("s_waitcnt vmcnt(0)" ::: "memory");
        __builtin_amdgcn_s_barrier();
        const unsigned short* Ab = Asm[kc & 1];
        const unsigned short* Bb = Bsm[kc & 1];
        #pragma unroll
        for (int ks = 0; ks < 2; ++ks) {
            bfrag a[4], b[4];
            #pragma unroll
            for (int i = 0; i < 4; ++i) {
                int ar = wm0 + i * 16 + (lane & 15);
                int ab = (ar * 128 + ks * 64 + (lane >> 4) * 16) ^ ((ar & 7) << 4);
                a[i] = *(const bfrag*)((const char*)Ab + ab);
                int br = wn0 + i * 16 + (lane & 15);
                int bb = (br * 128 + ks * 64 + (lane >> 4) * 16) ^ ((br & 7) << 4);
                b[i] = *(const bfrag*)((const char*)Bb + bb);
            }
            #pragma unroll
            for (int i = 0; i < 4; ++i)
                #pragma unroll
                for (int j = 0; j < 4; ++j)
                    acc[i][j] = __builtin_amdgcn_mfma_f32_16x16x32_bf16(a[i], b[j], acc[i][j], 0, 0, 0);
        }
        __builtin_amdgcn_s_barrier();
        if (kc + 2 < nK) STAGE(kc & 1, (kc + 2) * 64);
    }
    #pragma unroll
    for (int i = 0; i < 4; ++i) {
        #pragma unroll
        for (int r = 0; r < 4; ++r) {
            int m = m0 + wm0 + i * 16 + ((lane >> 4) << 2) + r;
            if (m >= M) continue;
            unsigned long long pm = 0ull;
            #pragma unroll
            for (int j = 0; j < 4; ++j) {
                int n = n0 + wn0 + j * 16 + (lane & 15);
                if (n >= N) continue;
                float v = acc[i][j][r];
                if (bias) v += bias[n];
                if (addmat) v += addmat[(size_t)(m & 127) * 2048 + n];
                size_t oi;
                if (outMode == 0) oi = (size_t)m * N + n;
                else { int bb2 = m & 127, tt = m >> 7; oi = ((size_t)bb2 * TT + tt) * (size_t)VV + n; }
                C[oi] = v;
                if (pmax) {
                    unsigned ub = __float_as_uint(v);
                    ub = (ub & 0x80000000u) ? ~ub : (ub | 0x80000000u);
                    unsigned long long key =
                        ((unsigned long long)ub << 13) | (unsigned)(8191 - n);
                    pm = pm > key ? pm : key;
                }
            }
            if (pmax) {
                // reduce across the 16 lanes sharing row m (xor stays in-group)
                #pragma unroll
                for (int s = 1; s < 16; s <<= 1) {
                    unsigned long long o =
                        (unsigned long long)__shfl_xor((long long)pm, s);
                    pm = pm > o ? pm : o;
                }
                if ((lane & 15) == 0) {
                    int bb2 = m & 127, tt = m >> 7;
                    atomicMax(&pmax[bb2 * TT + tt], pm);
                }
            }
        }
    }
}

// ---------- persistent LSTM v4: XCD-local (R12-proven) + reg-resident W-lo ----------
__global__ __launch_bounds__(256, 1) void lstm_persist4(
    unsigned short* __restrict__ H3,        // 28*128 x 1024 [hi|lo]
    const unsigned short* __restrict__ Whi, // 2048 quad rows x 512 (hi)
    const unsigned short* __restrict__ Wlo, // 2048 quad rows x 512 (lo)
    const float* __restrict__ xgb,          // 3456 x 2048 (xg + gb)
    unsigned* bar)                          // flags: xcd*2048+slot*16 ; ctr: 16384+xcd*16
{
    __shared__ unsigned short Wl[64 * 512];   // 65536 B (W-hi slice)
    __shared__ unsigned short Al[16 * 1024];  // 32768 B (A compact)
    __shared__ int s_ids[2];

    int tid = threadIdx.x, wv = tid >> 6, lane = tid & 63;
    if (tid == 0) {
        unsigned x;
        asm volatile("s_getreg_b32 %0, hwreg(HW_REG_XCC_ID)" : "=s"(x));
        x &= 7u;
        unsigned s = __hip_atomic_fetch_add(bar + 16384 + x * 16, 1u,
                        __ATOMIC_RELAXED, __HIP_MEMORY_SCOPE_AGENT);
        s_ids[0] = (int)x;
        s_ids[1] = (int)(s & 31u);
    }
    __syncthreads();
    int xcd = s_ids[0], slot = s_ids[1];
    int b0 = xcd * 16;              // batch rows [b0, b0+16)
    int nq0 = slot * 64;            // quad rows [nq0, nq0+64)

    int l15 = lane & 15, g4 = (lane >> 4) << 4;
    int arow = l15;                 // A row (m)
    int wr = wv * 16 + l15;         // W-hi LDS row (0..63)
    int n_local = wv * 16 + l15;
    int g = n_local & 3;            // gate
    int kglob = slot * 16 + (n_local >> 2);
    const unsigned short* wloRow = Wlo + (size_t)(nq0 + n_local) * 512;
    float creg[4] = {0.f, 0.f, 0.f, 0.f};

    // stage W-hi slice once: 64 rows x 512 elems (64 x 16B chunks per row)
    {
        const unsigned short* Wsrc = Whi + (size_t)nq0 * 512;
        #pragma unroll
        for (int j = 0; j < 16; ++j) {
            int ci = j * 256 + tid;
            int row = ci >> 6, cc = ci & 63;
            int sc = cc ^ (row & 7);
            gload16(Wl + ci * 8, Wsrc + (size_t)row * 512 + sc * 8);
        }
        asm volatile("s_waitcnt vmcnt(0)" ::: "memory");
    }
    // W-lo fragments are STEP-INVARIANT: preload once into registers
    bfrag wlo[16];
    #pragma unroll
    for (int c = 0; c < 16; ++c)
        wlo[c] = *(const bfrag*)(wloRow + c * 32 + (lane >> 4) * 8);
    __syncthreads();

    for (int t = 0; t < TT; ++t) {
        // stage A: 16 rows x 1024 elems via sc0 (fresh from own-XCD L2)
        const unsigned short* Asrc = H3 + ((size_t)t * 128 + b0) * 1024;
        #pragma unroll
        for (int j = 0; j < 8; ++j) {
            int ci = j * 256 + tid;
            int row = ci >> 7, cc = ci & 127;
            int sc = cc ^ (row & 7);
            gload16s(Al + ci * 8, Asrc + (size_t)row * 1024 + sc * 8);
        }
        // prefetch epilogue xgb values; counted vmcnt leaves them in flight
        float xpre[4];
        #pragma unroll
        for (int r = 0; r < 4; ++r) {
            int m_local = ((lane >> 4) << 2) + r;
            xpre[r] = xgb[(((size_t)t * 128 + b0 + m_local) << 11) + (size_t)g * 512 + kglob];
        }
        asm volatile("s_waitcnt vmcnt(4)" ::: "memory");   // A-stage (8) done; 4 xpre in flight
        __builtin_amdgcn_s_barrier();

        f32x4 acc0 = (f32x4){0.f, 0.f, 0.f, 0.f};
        f32x4 acc1 = acc0, acc2 = acc0, acc3 = acc0;
        // region 0: a=hi(c), w=hi(c)  [4 independent chains]
        #pragma unroll
        for (int c = 0; c < 16; ++c) {
            int ab = (arow * 2048 + c * 64 + g4) ^ ((arow & 7) << 4);
            int wb = (wr * 1024 + c * 64 + g4) ^ ((wr & 7) << 4);
            bfrag a = *(const bfrag*)((const char*)Al + ab);
            bfrag w = *(const bfrag*)((const char*)Wl + wb);
            switch (c & 3) {
                case 0: acc0 = __builtin_amdgcn_mfma_f32_16x16x32_bf16(a, w, acc0, 0, 0, 0); break;
                case 1: acc1 = __builtin_amdgcn_mfma_f32_16x16x32_bf16(a, w, acc1, 0, 0, 0); break;
                case 2: acc2 = __builtin_amdgcn_mfma_f32_16x16x32_bf16(a, w, acc2, 0, 0, 0); break;
                default: acc3 = __builtin_amdgcn_mfma_f32_16x16x32_bf16(a, w, acc3, 0, 0, 0); break;
            }
        }
        // region 1: a=hi(c), w=lo(c) from REGISTERS (pure-reg MFMA)
        #pragma unroll
        for (int c = 0; c < 16; ++c) {
            int ab = (arow * 2048 + c * 64 + g4) ^ ((arow & 7) << 4);
            bfrag a = *(const bfrag*)((const char*)Al + ab);
            switch (c & 3) {
                case 0: acc0 = __builtin_amdgcn_mfma_f32_16x16x32_bf16(a, wlo[c], acc0, 0, 0, 0); break;
                case 1: acc1 = __builtin_amdgcn_mfma_f32_16x16x32_bf16(a, wlo[c], acc1, 0, 0, 0); break;
                case 2: acc2 = __builtin_amdgcn_mfma_f32_16x16x32_bf16(a, wlo[c], acc2, 0, 0, 0); break;
                default: acc3 = __builtin_amdgcn_mfma_f32_16x16x32_bf16(a, wlo[c], acc3, 0, 0, 0); break;
            }
        }
        // region 2: a=lo(16+c), w=hi(c)
        #pragma unroll
        for (int c = 0; c < 16; ++c) {
            int ab = (arow * 2048 + (16 + c) * 64 + g4) ^ ((arow & 7) << 4);
            int wb = (wr * 1024 + c * 64 + g4) ^ ((wr & 7) << 4);
            bfrag a = *(const bfrag*)((const char*)Al + ab);
            bfrag w = *(const bfrag*)((const char*)Wl + wb);
            switch (c & 3) {
                case 0: acc0 = __builtin_amdgcn_mfma_f32_16x16x32_bf16(a, w, acc0, 0, 0, 0); break;
                case 1: acc1 = __builtin_amdgcn_mfma_f32_16x16x32_bf16(a, w, acc1, 0, 0, 0); break;
                case 2: acc2 = __builtin_amdgcn_mfma_f32_16x16x32_bf16(a, w, acc2, 0, 0, 0); break;
                default: acc3 = __builtin_amdgcn_mfma_f32_16x16x32_bf16(a, w, acc3, 0, 0, 0); break;
            }
        }
        f32x4 accT = (acc0 + acc1) + (acc2 + acc3);

        // epilogue: xpre add, shfl-down gate gather, LSTM update, compact h write
        #pragma unroll
        for (int r = 0; r < 4; ++r) {
            int m_local = ((lane >> 4) << 2) + r;
            int b = b0 + m_local;
            float v = accT[r] + xpre[r];
            float f1 = __shfl_down(v, 1);
            float f2 = __shfl_down(v, 2);
            float f3 = __shfl_down(v, 3);
            if ((lane & 3) == 0) {
                float si = 1.f / (1.f + expf(-v));
                float sf = 1.f / (1.f + expf(-f1));
                float tg = tanhf(f2);
                float so = 1.f / (1.f + expf(-f3));
                float cn = sf * creg[r] + si * tg;
                float hn = so * tanhf(cn);
                creg[r] = cn;
                unsigned short hi = f2bf(hn);
                unsigned short lo = f2bf(hn - bf2f(hi));
                unsigned short* hr = H3 + ((size_t)(t + 1) * 128 + b) * 1024;
                hr[kglob] = hi; hr[512 + kglob] = lo;
            }
        }

        if (t != TT - 1) {
            // XCD-local barrier: stores committed to L2, then flag; 32 threads
            // poll the 32 per-slot flags in parallel. No fences, L2 stays warm.
            asm volatile("s_waitcnt vmcnt(0)" ::: "memory");
            __syncthreads();
            unsigned ph = (unsigned)(t + 1);
            if (tid == 0)
                __hip_atomic_store(bar + xcd * 2048 + slot * 16, ph,
                                   __ATOMIC_RELAXED, __HIP_MEMORY_SCOPE_AGENT);
            if (tid < 32) {
                unsigned* fl = bar + xcd * 2048 + tid * 16;
                while (__hip_atomic_load(fl, __ATOMIC_RELAXED,
                                         __HIP_MEMORY_SCOPE_AGENT) < ph)
                    __builtin_amdgcn_s_sleep(1);
            }
            __syncthreads();
        }
    }
}

// ---------- small helpers ----------
__global__ __launch_bounds__(512) void matvec_col_partial(
    const float* __restrict__ W, int ldw, int koff,
    const float* __restrict__ vin, float* __restrict__ part)
{
    int k = threadIdx.x;
    int o0 = blockIdx.x * 16;
    float acc = 0.f;
    #pragma unroll
    for (int o = 0; o < 16; ++o)
        acc += W[(size_t)(o0 + o) * ldw + koff + k] * vin[o0 + o];
    part[blockIdx.x * 512 + k] = acc;
}

__global__ __launch_bounds__(512) void matvec_combine(
    const float* __restrict__ part, float* __restrict__ vout)
{
    int k = threadIdx.x;
    float s = 0.f;
    #pragma unroll
    for (int c = 0; c < 32; ++c) s += part[c * 512 + k];
    vout[k] = s;
}

__global__ __launch_bounds__(256) void attn_ctx(
    const float* __restrict__ enc, const float* __restrict__ u,
    float* __restrict__ ctx)
{
    __shared__ float su[HH];
    __shared__ float sw[SS];
    __shared__ float ssum;
    int b = blockIdx.x, tid = threadIdx.x;
    su[tid] = u[tid];
    su[tid + 256] = u[tid + 256];
    __syncthreads();
    const float* eb = enc + (size_t)b * SS * HH;
    int wave = tid >> 6, lane = tid & 63;
    for (int s = wave; s < SS; s += 4) {
        const float* row = eb + s * HH;
        float acc = 0.f;
        for (int k = lane; k < HH; k += 64) acc += row[k] * su[k];
        #pragma unroll
        for (int off = 32; off; off >>= 1) acc += __shfl_down(acc, off);
        if (lane == 0) sw[s] = acc;
    }
    __syncthreads();
    if (tid == 0) {
        float mx = sw[0];
        for (int s = 1; s < SS; ++s) mx = fmaxf(mx, sw[s]);
        float sum = 0.f;
        for (int s = 0; s < SS; ++s) { float e = expf(sw[s] - mx); sw[s] = e; sum += e; }
        ssum = sum;
    }
    __syncthreads();
    float inv = 1.0f / ssum;
    for (int k = tid; k < HH; k += 256) {
        float acc = 0.f;
        #pragma unroll 4
        for (int s = 0; s < SS; ++s) acc += sw[s] * eb[s * HH + k];
        ctx[(size_t)b * HH + k] = acc * inv;
    }
}

// fp32 vector GEMM, kept only for gbase (ctx @ Wc^T + b_ih + b_hh)
__global__ __launch_bounds__(256) void gemm_nt(
    int M, int N, int K,
    const float* __restrict__ A, int lda,
    const float* __restrict__ Bm, int ldb, int kob,
    const float* __restrict__ bias1, const float* __restrict__ bias2,
    float* __restrict__ C)
{
    __shared__ float As[16][132];
    __shared__ float Bs[16][132];
    int tid = threadIdx.x;
    int m0 = blockIdx.y * 128, n0 = blockIdx.x * 128;
    int tn = tid & 15, tm = tid >> 4;
    float acc[8][8];
    #pragma unroll
    for (int i = 0; i < 8; ++i)
        #pragma unroll
        for (int j = 0; j < 8; ++j) acc[i][j] = 0.f;
    int lr = tid >> 2;
    int lk = (tid & 3) * 4;
    for (int k0 = 0; k0 < K; k0 += 16) {
        #pragma unroll
        for (int half = 0; half < 2; ++half) {
            int mr = lr + half * 64;
            int m = m0 + mr;
            float4 va = make_float4(0.f, 0.f, 0.f, 0.f);
            if (m < M) va = *(const float4*)(A + (size_t)m * lda + k0 + lk);
            As[lk + 0][mr] = va.x; As[lk + 1][mr] = va.y;
            As[lk + 2][mr] = va.z; As[lk + 3][mr] = va.w;
            int n = n0 + mr;
            float4 vb = make_float4(0.f, 0.f, 0.f, 0.f);
            if (n < N) vb = *(const float4*)(Bm + (size_t)n * ldb + kob + k0 + lk);
            Bs[lk + 0][mr] = vb.x; Bs[lk + 1][mr] = vb.y;
            Bs[lk + 2][mr] = vb.z; Bs[lk + 3][mr] = vb.w;
        }
        __syncthreads();
        #pragma unroll
        for (int kk = 0; kk < 16; ++kk) {
            float4 a0 = *(const float4*)&As[kk][tm * 8];
            float4 a1 = *(const float4*)&As[kk][tm * 8 + 4];
            float4 b0 = *(const float4*)&Bs[kk][tn * 8];
            float4 b1 = *(const float4*)&Bs[kk][tn * 8 + 4];
            float av[8] = {a0.x, a0.y, a0.z, a0.w, a1.x, a1.y, a1.z, a1.w};
            float bv[8] = {b0.x, b0.y, b0.z, b0.w, b1.x, b1.y, b1.z, b1.w};
            #pragma unroll
            for (int i = 0; i < 8; ++i)
                #pragma unroll
                for (int j = 0; j < 8; ++j)
                    acc[i][j] += av[i] * bv[j];
        }
        __syncthreads();
    }
    #pragma unroll
    for (int i = 0; i < 8; ++i) {
        int m = m0 + tm * 8 + i;
        if (m >= M) continue;
        #pragma unroll
        for (int j = 0; j < 8; ++j) {
            int n = n0 + tn * 8 + j;
            if (n >= N) continue;
            float v = acc[i][j];
            if (bias1) v += bias1[n];
            if (bias2) v += bias2[n];
            C[(size_t)m * N + n] = v;
        }
    }
}

extern "C" void kernel_launch(void* const* d_in, const int* in_sizes, int n_in,
                              void* d_out, int out_size, void* d_ws, size_t ws_size,
                              hipStream_t stream) {
    const float* ehs   = (const float*)d_in[0];
    const float* enc   = (const float*)d_in[1];
    const int*   tgt   = (const int*)d_in[2];
    const float* emb   = (const float*)d_in[4];
    const float* fc1w  = (const float*)d_in[5];
    const float* fc2w  = (const float*)d_in[7];
    const float* fc3w  = (const float*)d_in[9];
    const float* fc4w  = (const float*)d_in[11];
    const float* attnw = (const float*)d_in[13];
    const float* wih   = (const float*)d_in[14];
    const float* whh   = (const float*)d_in[15];
    const float* bih   = (const float*)d_in[16];
    const float* bhh   = (const float*)d_in[17];
    const float* outw  = (const float*)d_in[18];
    const float* outb  = (const float*)d_in[19];
    float* out = (float*)d_out;
    float* ws  = (float*)d_ws;

    float* vA   = ws + OFF_VA;
    float* vB   = ws + OFF_VB;
    float* u    = ws + OFF_U;
    float* part = ws + OFF_PART;
    float* ctx  = ws + OFF_CTX;
    float* gb   = ws + OFF_GB;
    float* xg   = ws + OFF_XG;
    unsigned* bar = (unsigned*)(ws + OFF_BAR);
    unsigned long long* pmax = (unsigned long long*)(bar + 16512);
    unsigned short* bfb = (unsigned short*)(ws + FP32_WS_FLOATS);
    unsigned short* H3   = bfb + O_H3;
    unsigned short* WHI  = bfb + O_WHI;
    unsigned short* WLO  = bfb + O_WLO;
    unsigned short* A3X  = bfb + O_A3X;
    unsigned short* B3X  = bfb + O_B3X;
    unsigned short* B3L  = bfb + O_B3L;

    // u = W1e^T W2^T W3^T W4^T attn_w
    matvec_col_partial<<<32, 512, 0, stream>>>(fc4w, 512, 0, attnw, part);
    matvec_combine<<<1, 512, 0, stream>>>(part, vA);
    matvec_col_partial<<<32, 512, 0, stream>>>(fc3w, 512, 0, vA, part);
    matvec_combine<<<1, 512, 0, stream>>>(part, vB);
    matvec_col_partial<<<32, 512, 0, stream>>>(fc2w, 512, 0, vB, part);
    matvec_combine<<<1, 512, 0, stream>>>(part, vA);
    matvec_col_partial<<<32, 512, 0, stream>>>(fc1w, 1024, 0, vA, part);
    matvec_combine<<<1, 512, 0, stream>>>(part, u);

    attn_ctx<<<128, 256, 0, stream>>>(enc, u, ctx);

    // gbase = ctx @ Wc^T + b_ih + b_hh  (fp32 path, tiny)
    {
        dim3 g(16, 1);
        gemm_nt<<<g, 256, 0, stream>>>(128, 2048, 512, ctx, 512,
                                       wih, 1536, 1024, bih, bhh, gb);
    }

    // xgb = gather(emb, tgt) @ Wx^T + gb  via split-bf16 MFMA (compact operands)
    conv_cpk<<<2048, 256, 0, stream>>>(wih, 1536, 1024, 0, nullptr, B3X);
    conv_cpk<<<3456, 256, 0, stream>>>(emb, 1024, 1024, 1, tgt, A3X);
    {
        dim3 g(16, 27);
        gemm_bf16_nt<<<g, 256, 0, stream>>>(3456, 2048, 3072,
                                            A3X, 2048, 1024,
                                            B3X, 2048, 1024,
                                            nullptr, gb, xg, 0, nullptr);
    }

    // B3L overlays A3X/B3X — only after the xg gemm
    conv_cpk<<<8000, 256, 0, stream>>>(outw, 512, 512, 0, nullptr, B3L);
    // whh -> quad-interleaved hi/lo arrays
    conv_splitw<<<2048, 256, 0, stream>>>(whh, WHI, WLO);
    // h0 -> H3[0] compact [hi|lo]
    conv_cpk<<<128, 256, 0, stream>>>(ehs, 512, 512, 0, nullptr, H3);

    // zero bar flags + pmax (argmax accumulators) every call
    zero_bar<<<92, 256, 0, stream>>>(bar);

    // persistent LSTM v4 (27 steps), XCD-local exchange + per-XCD flag barrier
    lstm_persist4<<<256, 256, 0, stream>>>(H3, WHI, WLO, xg, bar);

    // logits = H3[1:] @ B3L^T + out_b, scattered to (b, t, v), FUSED row-argmax
    {
        dim3 g(63, 27);
        gemm_bf16_nt<<<g, 256, 0, stream>>>(3456, 8000, 1536,
                                            H3 + (size_t)128 * 1024, 1024, 512,
                                            B3L, 1024, 512,
                                            outb, nullptr, out, 1, pmax);
    }

    // preds from packed argmax keys
    unpack_preds<<<14, 256, 0, stream>>>(pmax, out + (size_t)TT * 128 * VV);
}